// Round 5
// baseline (436.965 us; speedup 1.0000x reference)
//
#include <hip/hip_runtime.h>
#include <cstdint>
#include <cstddef>

// Problem constants (fixed by setup_inputs)
#define NB 4      // batch
#define NT 12     // timesteps
#define NN 2048   // nodes
#define NF 64     // in features
#define NH 4      // heads
#define ND 16     // head dim
#define NC 64     // out channels
#define MAXD 64   // max neighbors kept (Binomial(2047,16/2048): P(deg>64)~1e-19)
#define NR (NB * NT * NN)  // 98304 batched GEMM rows

typedef _Float16 f16x8 __attribute__((ext_vector_type(8)));
typedef _Float16 f16x2 __attribute__((ext_vector_type(2)));
typedef float f32x4 __attribute__((ext_vector_type(4)));

#define LR(v) ((v) >= 0.f ? (v) : 0.2f * (v))
#define RCPF(x) __builtin_amdgcn_rcpf(x)

// v_fma_mix_f32: acc += w * (f32)(f16 half of d).
#define MACLO(acc, w, d)                                                      \
  asm("v_fma_mix_f32 %0, %1, %2, %0 op_sel:[0,0,0] op_sel_hi:[0,1,0]"         \
      : "+v"(acc) : "v"(w), "v"(d))
#define MACHI(acc, w, d)                                                      \
  asm("v_fma_mix_f32 %0, %1, %2, %0 op_sel:[0,1,0] op_sel_hi:[0,1,0]"         \
      : "+v"(acc) : "v"(w), "v"(d))

// ---------------------------------------------------------------------------
// Build padded adjacency lists from the additive mask (0 / -1e9), one wave/row.
// Also zeroes the 8 per-XCD ticket counters used by attn_gru_k (runs before
// it on the same stream every graph replay).
__global__ __launch_bounds__(256) void build_adj_k(const float* __restrict__ bias,
                                                   int* __restrict__ adj,
                                                   int* __restrict__ deg,
                                                   int* __restrict__ ctr) {
  if (blockIdx.x < 8 && threadIdx.x == 0) ctr[blockIdx.x] = 0;
  int gtid = blockIdx.x * 256 + threadIdx.x;
  int wid = gtid >> 6;            // row id in [0, NB*NN)
  int lane = threadIdx.x & 63;
  if (wid >= NB * NN) return;
  const float* row = bias + (size_t)wid * NN;
  int* arow = adj + (size_t)wid * MAXD;
  int count = 0;
  for (int c0 = 0; c0 < NN; c0 += 64) {
    float v = __builtin_nontemporal_load(row + c0 + lane);  // 67 MB single-use
    bool e = (v > -1e8f);                       // edge iff mask == 0
    unsigned long long m = __ballot(e);
    int pre = __popcll(m & ((1ull << lane) - 1ull));
    if (e) {
      int pos = count + pre;
      if (pos < MAXD) arow[pos] = c0 + lane;
    }
    count += __popcll(m);
  }
  if (lane == 0) deg[wid] = count < MAXD ? count : MAXD;
}

// ---------------------------------------------------------------------------
// One-shot weight prep: fp16 W16[272][64] in B-fragment layout + biasC[128].
__global__ __launch_bounds__(256) void prep_w_k(
    const float* __restrict__ Wgz, const float* __restrict__ Wgh,
    const float* __restrict__ Wz,  const float* __restrict__ Wh,
    const float* __restrict__ a1z, const float* __restrict__ a2z,
    const float* __restrict__ a1h, const float* __restrict__ a2h,
    const float* __restrict__ Zb,  const float* __restrict__ Hb,
    _Float16* __restrict__ W16, float* __restrict__ biasC) {
  int idx = blockIdx.x * 256 + threadIdx.x;
  if (idx < 272 * 64) {
    int c = idx >> 6, k = idx & 63;
    float w;
    if (c < 64)       w = Wgz[((c >> 4) << 10) + (k << 4) + (c & 15)];
    else if (c < 128) { int q = c - 64; w = Wgh[((q >> 4) << 10) + (k << 4) + (q & 15)]; }
    else if (c < 192) w = Wz[(k << 6) + (c - 128)];
    else if (c < 256) w = Wh[(k << 6) + (c - 192)];
    else {
      int j = c - 256, h = j & 3;
      const float* Wg = (j & 4) ? Wgh : Wgz;
      const float* av = (j & 8) ? ((j & 4) ? a2h : a2z) : ((j & 4) ? a1h : a1z);
      float s = 0.f;
#pragma unroll
      for (int d = 0; d < 16; d++)
        s = fmaf(Wg[(h << 10) + (k << 4) + d], av[(h << 4) + d], s);
      w = s;
    }
    W16[idx] = (_Float16)w;
  }
  if (blockIdx.x == 0 && threadIdx.x < 128)
    biasC[threadIdx.x] =
        (threadIdx.x < 64) ? Zb[threadIdx.x] : Hb[threadIdx.x - 64];
}

// ---------------------------------------------------------------------------
// fp16 MFMA GEMM: [98304 x 64] @ [64 x 272], fp32 accumulate. (unchanged)
__global__ __launch_bounds__(256) void mfma_gemm_k(
    const float* __restrict__ X, const _Float16* __restrict__ W16,
    const float* __restrict__ biasC,
    uint32_t* __restrict__ gbufF, uint32_t* __restrict__ gbufS,
    float* __restrict__ fbuf) {
  __shared__ uint32_t tr[4][16 * 68];   // per-wave 16 rows x 64 cols (+pad)
  const int tid = threadIdx.x;
  const int wv = tid >> 6, lane = tid & 63;
  const int m = lane & 15, quad = lane >> 4;
  const unsigned rw = blockIdx.x * 64 + wv * 16;      // wave's row base
  uint32_t* tw = tr[wv];

  const float* xr = X + (size_t)(rw + m) * 64;
  float4 x0 = *(const float4*)(xr + quad * 8);
  float4 x1 = *(const float4*)(xr + quad * 8 + 4);
  float4 x2 = *(const float4*)(xr + 32 + quad * 8);
  float4 x3 = *(const float4*)(xr + 32 + quad * 8 + 4);
  f16x8 A0 = {(_Float16)x0.x, (_Float16)x0.y, (_Float16)x0.z, (_Float16)x0.w,
              (_Float16)x1.x, (_Float16)x1.y, (_Float16)x1.z, (_Float16)x1.w};
  f16x8 A1 = {(_Float16)x2.x, (_Float16)x2.y, (_Float16)x2.z, (_Float16)x2.w,
              (_Float16)x3.x, (_Float16)x3.y, (_Float16)x3.z, (_Float16)x3.w};

  float bzc[4], bhc[4];
#pragma unroll
  for (int j = 0; j < 4; j++) {
    bzc[j] = biasC[j * 16 + m];
    bhc[j] = biasC[64 + j * 16 + m];
  }
  const int rsub = lane >> 4, chk = lane & 15;   // readback: row-sub, chunk

  f32x4 zacc[4], zs[4];
#pragma unroll
  for (int ct = 0; ct < 17; ct++) {
    const _Float16* wp = W16 + (ct * 16 + m) * 64;
    f16x8 B0 = *(const f16x8*)(wp + quad * 8);
    f16x8 B1 = *(const f16x8*)(wp + 32 + quad * 8);
    f32x4 acc = {0.f, 0.f, 0.f, 0.f};
    acc = __builtin_amdgcn_mfma_f32_16x16x32_f16(A0, B0, acc, 0, 0, 0);
    acc = __builtin_amdgcn_mfma_f32_16x16x32_f16(A1, B1, acc, 0, 0, 0);
    // C-layout: row = quad*4 + r, col = ct*16 + m  [measured: learn_hip m89]
    if (ct < 4) {
      zacc[ct] = acc;                        // z-feat tiles, saved for pairing
    } else if (ct < 8) {
      const int j = ct - 4;                  // h-feat tile -> pack {z,h}
#pragma unroll
      for (int r = 0; r < 4; r++) {
        f16x2 pv = {(_Float16)zacc[j][r], (_Float16)acc[r]};
        tw[(quad * 4 + r) * 68 + j * 16 + m] = __builtin_bit_cast(uint32_t, pv);
      }
      if (ct == 7) {   // full-tile readback: 4 stores x (16 lanes = 256B row)
#pragma unroll
        for (int i = 0; i < 4; i++) {
          int row = i * 4 + rsub;
          uint4 v = *(const uint4*)&tw[row * 68 + chk * 4];
          *(uint4*)&gbufF[(size_t)(rw + row) * 64 + chk * 4] = v;
        }
      }
    } else if (ct < 12) {
#pragma unroll
      for (int r = 0; r < 4; r++) zs[ct - 8][r] = acc[r] + bzc[ct - 8];
    } else if (ct < 16) {
      const int j = ct - 12;
#pragma unroll
      for (int r = 0; r < 4; r++) {
        f16x2 pv = {(_Float16)zs[j][r], (_Float16)(acc[r] + bhc[j])};
        tw[(quad * 4 + r) * 68 + j * 16 + m] = __builtin_bit_cast(uint32_t, pv);
      }
      if (ct == 15) {
#pragma unroll
        for (int i = 0; i < 4; i++) {
          int row = i * 4 + rsub;
          uint4 v = *(const uint4*)&tw[row * 68 + chk * 4];
          *(uint4*)&gbufS[(size_t)(rw + row) * 64 + chk * 4] = v;
        }
      }
    } else {
      const unsigned rb = rw + quad * 4;
#pragma unroll
      for (int r = 0; r < 4; r++) fbuf[(size_t)(rb + r) * 16 + m] = acc[r];
    }
  }
}

// ---------------------------------------------------------------------------
// Fused attention + GRU, R4: dynamic per-XCD work-stealing + register-hoisted
// gather offsets.
//  - Grid 1024 blocks (4096 waves). Each wave pulls nodes from its XCD
//    group's ticket counter (g = bid&7, nodes [g*1024,(g+1)*1024)): greedy
//    balance kills the degree-imbalance tail (R3: 40% avg occupancy from
//    100%->0 decay), while preserving the batch/L2 affinity swizzle.
//  - Gather byte-offsets (m<<8)+(ch<<2) are t-invariant: hoisted into 8 uint4
//    regs per node (covers deg<=32; LDS fallback for the ~3 rarer nodes).
//    All batch loads issue before any MAC (guards branch on uniform SGPR,
//    no memory dependence) -> 24-32 loads in flight, zero per-load VALU.
//  - Keeps: cross-t feature prefetch, self pre-gate prefetch, fma_mix MACs,
//    cooperative row-sum reduce, f32 GRU + fused BN.
__global__ __launch_bounds__(256, 4) void attn_gru_k(
    const uint32_t* __restrict__ gbufF, const uint32_t* __restrict__ gbufS,
    const float* __restrict__ fbuf,
    const int* __restrict__ adj, const int* __restrict__ deg,
    const float* __restrict__ bgz, const float* __restrict__ bgh,
    const float* __restrict__ gam, const float* __restrict__ bet,
    const float* __restrict__ mu, const float* __restrict__ var,
    int* __restrict__ ctr, float* __restrict__ out) {
  __shared__ int adjL[4][MAXD];
  __shared__ float wexp[4][8][68];      // stride 68 kills head-alias
  const int tid = threadIdx.x;
  const int lane = tid & 63;
  const int ws = tid >> 6;
  const int g = blockIdx.x & 7;         // XCD group; nodes [g*1024,(g+1)*1024)
  const int ch = lane, hh = lane >> 4;
  const uint32_t ch4 = (uint32_t)ch << 2;
  const int sr = lane & 7, ss = lane >> 3;   // sum-reduce: row, segment

  // Per-channel constants (hoisted out of the ticket loop)
  const float bz = bgz[ch], bh = bgh[ch];
  const float bnm = mu[ch];
  const float bns = rsqrtf(var[ch] + 1e-3f);
  const float bng = gam[ch], bnb = bet[ch];

  int* ctrg = ctr + g;
  for (;;) {
    int tk = 0;
    if (lane == 0) tk = atomicAdd(ctrg, 1);
    tk = __shfl(tk, 0);
    if (tk >= NN * NB / 8) break;       // 1024 nodes per group
    const int node = g * (NN * NB / 8) + tk;
    const int b = node >> 11;
    const int nl = node & (NN - 1);
    const int dg = deg[node];
    const int myadj = (lane < dg) ? adj[node * MAXD + lane] : 0;
    adjL[ws][lane] = myadj;
    const int dgp4 = (dg + 3) & ~3;
    const int dgp8 = (dg + 7) & ~7;

    // Zero all wexp rows: pad slots (>= dg) stay 0 for every t (inert in
    // both the row sums and the gather). Re-zeroed per node (dg varies).
#pragma unroll
    for (int k = 0; k < 8; k++) wexp[ws][k][lane] = 0.f;

    // ---- hoist t-invariant gather byte-offsets into registers ----
    // (row m of gbuf = 64 dwords = 256 B). Pad slots -> row 0 (safe, w=0).
    uint4 o0, o1, o2, o3, o4, o5, o6, o7;
    {
      int4 A0 = *(const int4*)&adjL[ws][0];
      int4 A1 = *(const int4*)&adjL[ws][4];
      o0 = {(uint32_t)(A0.x << 8) + ch4, (uint32_t)(A0.y << 8) + ch4,
            (uint32_t)(A0.z << 8) + ch4, (uint32_t)(A0.w << 8) + ch4};
      o1 = {(uint32_t)(A1.x << 8) + ch4, (uint32_t)(A1.y << 8) + ch4,
            (uint32_t)(A1.z << 8) + ch4, (uint32_t)(A1.w << 8) + ch4};
      if (dgp8 > 8) {
        int4 A2 = *(const int4*)&adjL[ws][8];
        int4 A3 = *(const int4*)&adjL[ws][12];
        o2 = {(uint32_t)(A2.x << 8) + ch4, (uint32_t)(A2.y << 8) + ch4,
              (uint32_t)(A2.z << 8) + ch4, (uint32_t)(A2.w << 8) + ch4};
        o3 = {(uint32_t)(A3.x << 8) + ch4, (uint32_t)(A3.y << 8) + ch4,
              (uint32_t)(A3.z << 8) + ch4, (uint32_t)(A3.w << 8) + ch4};
      }
      if (dgp8 > 16) {
        int4 A4 = *(const int4*)&adjL[ws][16];
        int4 A5 = *(const int4*)&adjL[ws][20];
        o4 = {(uint32_t)(A4.x << 8) + ch4, (uint32_t)(A4.y << 8) + ch4,
              (uint32_t)(A4.z << 8) + ch4, (uint32_t)(A4.w << 8) + ch4};
        o5 = {(uint32_t)(A5.x << 8) + ch4, (uint32_t)(A5.y << 8) + ch4,
              (uint32_t)(A5.z << 8) + ch4, (uint32_t)(A5.w << 8) + ch4};
      }
      if (dgp8 > 24) {
        int4 A6 = *(const int4*)&adjL[ws][24];
        int4 A7 = *(const int4*)&adjL[ws][28];
        o6 = {(uint32_t)(A6.x << 8) + ch4, (uint32_t)(A6.y << 8) + ch4,
              (uint32_t)(A6.z << 8) + ch4, (uint32_t)(A6.w << 8) + ch4};
        o7 = {(uint32_t)(A7.x << 8) + ch4, (uint32_t)(A7.y << 8) + ch4,
              (uint32_t)(A7.z << 8) + ch4, (uint32_t)(A7.w << 8) + ch4};
      }
    }

    // Rotating feature registers: f1 (own row, bcast) + f2 (lane's neighbor).
    float4 c1z, c1h, c2z, c2h;
    {
      const float* fb0 = fbuf + (size_t)(b * NT) * NN * 16;
      const float4* p0 = (const float4*)(fb0 + nl * 16);
      const float4* q0 = (const float4*)(fb0 + (size_t)myadj * 16);
      c1z = p0[0]; c1h = p0[1]; c2z = q0[2]; c2h = q0[3];
    }

    float hc = 0.f;
#pragma unroll 1
    for (int t = 0; t < NT; t++) {
      const unsigned rb = (unsigned)(b * NT + t) * NN;
      const uint32_t* gF = gbufF + (size_t)rb * 64;
      // self pre-gate dword: issue now, consumed in epilogue
      const uint32_t spd = gbufS[((size_t)rb + nl) * 64 + ch];

      // ---- phase 1: raw exp attention weights from prefetched regs ----
      float e0 = __expf(LR(c1z.x + c2z.x));
      float e1 = __expf(LR(c1z.y + c2z.y));
      float e2 = __expf(LR(c1z.z + c2z.z));
      float e3 = __expf(LR(c1z.w + c2z.w));
      float e4 = __expf(LR(c1h.x + c2h.x));
      float e5 = __expf(LR(c1h.y + c2h.y));
      float e6 = __expf(LR(c1h.z + c2h.z));
      float e7 = __expf(LR(c1h.w + c2h.w));
      if (lane < dg) {                    // masked: pad slots stay 0
        wexp[ws][0][lane] = e0;
        wexp[ws][1][lane] = e1;
        wexp[ws][2][lane] = e2;
        wexp[ws][3][lane] = e3;
        wexp[ws][4][lane] = e4;
        wexp[ws][5][lane] = e5;
        wexp[ws][6][lane] = e6;
        wexp[ws][7][lane] = e7;
      }

      // ---- issue t+1 feature prefetch (hidden under reduce+gather) ----
      if (t + 1 < NT) {
        const float* fbn = fbuf + ((size_t)rb + NN) * 16;
        const float4* pn = (const float4*)(fbn + nl * 16);
        const float4* qn = (const float4*)(fbn + (size_t)myadj * 16);
        c1z = pn[0]; c1h = pn[1]; c2z = qn[2]; c2h = qn[3];
      }

      // ---- phase 1.5: cooperative row sums ----
      float4 u0 = *(const float4*)&wexp[ws][sr][ss * 8];
      float4 u1 = *(const float4*)&wexp[ws][sr][ss * 8 + 4];
      float part = ((u0.x + u0.y) + (u0.z + u0.w)) +
                   ((u1.x + u1.y) + (u1.z + u1.w));
      part += __shfl_xor(part, 8);
      part += __shfl_xor(part, 16);
      part += __shfl_xor(part, 32);
      const float rsz = RCPF(__shfl(part, hh));
      const float rsh = RCPF(__shfl(part, 4 + hh));

      // ---- phase 2: all loads issued first (24-32 in flight), then MACs ----
      float az = 0.f, ah = 0.f;
      const float* wz = wexp[ws][hh];
      const float* wh = wexp[ws][4 + hh];
      const char* gFb = (const char*)gF;
      uint32_t d00, d01, d02, d03, d04, d05, d06, d07;
      uint32_t d10, d11, d12, d13, d14, d15, d16, d17;
      uint32_t d20, d21, d22, d23, d24, d25, d26, d27;
      uint32_t d30, d31, d32, d33, d34, d35, d36, d37;
      d00 = *(const uint32_t*)(gFb + o0.x);
      d01 = *(const uint32_t*)(gFb + o0.y);
      d02 = *(const uint32_t*)(gFb + o0.z);
      d03 = *(const uint32_t*)(gFb + o0.w);
      d04 = *(const uint32_t*)(gFb + o1.x);
      d05 = *(const uint32_t*)(gFb + o1.y);
      d06 = *(const uint32_t*)(gFb + o1.z);
      d07 = *(const uint32_t*)(gFb + o1.w);
      if (dgp8 > 8) {
        d10 = *(const uint32_t*)(gFb + o2.x);
        d11 = *(const uint32_t*)(gFb + o2.y);
        d12 = *(const uint32_t*)(gFb + o2.z);
        d13 = *(const uint32_t*)(gFb + o2.w);
        d14 = *(const uint32_t*)(gFb + o3.x);
        d15 = *(const uint32_t*)(gFb + o3.y);
        d16 = *(const uint32_t*)(gFb + o3.z);
        d17 = *(const uint32_t*)(gFb + o3.w);
      }
      if (dgp8 > 16) {
        d20 = *(const uint32_t*)(gFb + o4.x);
        d21 = *(const uint32_t*)(gFb + o4.y);
        d22 = *(const uint32_t*)(gFb + o4.z);
        d23 = *(const uint32_t*)(gFb + o4.w);
        d24 = *(const uint32_t*)(gFb + o5.x);
        d25 = *(const uint32_t*)(gFb + o5.y);
        d26 = *(const uint32_t*)(gFb + o5.z);
        d27 = *(const uint32_t*)(gFb + o5.w);
      }
      if (dgp8 > 24) {
        d30 = *(const uint32_t*)(gFb + o6.x);
        d31 = *(const uint32_t*)(gFb + o6.y);
        d32 = *(const uint32_t*)(gFb + o6.z);
        d33 = *(const uint32_t*)(gFb + o6.w);
        d34 = *(const uint32_t*)(gFb + o7.x);
        d35 = *(const uint32_t*)(gFb + o7.y);
        d36 = *(const uint32_t*)(gFb + o7.z);
        d37 = *(const uint32_t*)(gFb + o7.w);
      }
      {
        float4 wza = *(const float4*)&wz[0], wzb = *(const float4*)&wz[4];
        float4 wha = *(const float4*)&wh[0], whb = *(const float4*)&wh[4];
        MACLO(az, wza.x, d00); MACHI(ah, wha.x, d00);
        MACLO(az, wza.y, d01); MACHI(ah, wha.y, d01);
        MACLO(az, wza.z, d02); MACHI(ah, wha.z, d02);
        MACLO(az, wza.w, d03); MACHI(ah, wha.w, d03);
        MACLO(az, wzb.x, d04); MACHI(ah, whb.x, d04);
        MACLO(az, wzb.y, d05); MACHI(ah, whb.y, d05);
        MACLO(az, wzb.z, d06); MACHI(ah, whb.z, d06);
        MACLO(az, wzb.w, d07); MACHI(ah, whb.w, d07);
      }
      if (dgp8 > 8) {
        float4 wza = *(const float4*)&wz[8], wzb = *(const float4*)&wz[12];
        float4 wha = *(const float4*)&wh[8], whb = *(const float4*)&wh[12];
        MACLO(az, wza.x, d10); MACHI(ah, wha.x, d10);
        MACLO(az, wza.y, d11); MACHI(ah, wha.y, d11);
        MACLO(az, wza.z, d12); MACHI(ah, wha.z, d12);
        MACLO(az, wza.w, d13); MACHI(ah, wha.w, d13);
        MACLO(az, wzb.x, d14); MACHI(ah, whb.x, d14);
        MACLO(az, wzb.y, d15); MACHI(ah, whb.y, d15);
        MACLO(az, wzb.z, d16); MACHI(ah, whb.z, d16);
        MACLO(az, wzb.w, d17); MACHI(ah, whb.w, d17);
      }
      if (dgp8 > 16) {
        float4 wza = *(const float4*)&wz[16], wzb = *(const float4*)&wz[20];
        float4 wha = *(const float4*)&wh[16], whb = *(const float4*)&wh[20];
        MACLO(az, wza.x, d20); MACHI(ah, wha.x, d20);
        MACLO(az, wza.y, d21); MACHI(ah, wha.y, d21);
        MACLO(az, wza.z, d22); MACHI(ah, wha.z, d22);
        MACLO(az, wza.w, d23); MACHI(ah, wha.w, d23);
        MACLO(az, wzb.x, d24); MACHI(ah, whb.x, d24);
        MACLO(az, wzb.y, d25); MACHI(ah, whb.y, d25);
        MACLO(az, wzb.z, d26); MACHI(ah, whb.z, d26);
        MACLO(az, wzb.w, d27); MACHI(ah, whb.w, d27);
      }
      if (dgp8 > 24) {
        float4 wza = *(const float4*)&wz[24], wzb = *(const float4*)&wz[28];
        float4 wha = *(const float4*)&wh[24], whb = *(const float4*)&wh[28];
        MACLO(az, wza.x, d30); MACHI(ah, wha.x, d30);
        MACLO(az, wza.y, d31); MACHI(ah, wha.y, d31);
        MACLO(az, wza.z, d32); MACHI(ah, wha.z, d32);
        MACLO(az, wza.w, d33); MACHI(ah, wha.w, d33);
        MACLO(az, wzb.x, d34); MACHI(ah, whb.x, d34);
        MACLO(az, wzb.y, d35); MACHI(ah, whb.y, d35);
        MACLO(az, wzb.z, d36); MACHI(ah, whb.z, d36);
        MACLO(az, wzb.w, d37); MACHI(ah, whb.w, d37);
      }
      // LDS-fallback tail for the rare deg>32 nodes (~1e-4 tail * 8192)
      for (int mi = 32; mi < dgp4; mi += 4) {
        int4 ma = *(const int4*)&adjL[ws][mi];
        uint32_t t0 = gF[(ma.x << 6) + ch];
        uint32_t t1 = gF[(ma.y << 6) + ch];
        uint32_t t2 = gF[(ma.z << 6) + ch];
        uint32_t t3 = gF[(ma.w << 6) + ch];
        float4 wza = *(const float4*)&wz[mi];
        float4 wha = *(const float4*)&wh[mi];
        MACLO(az, wza.x, t0); MACHI(ah, wha.x, t0);
        MACLO(az, wza.y, t1); MACHI(ah, wha.y, t1);
        MACLO(az, wza.z, t2); MACHI(ah, wha.z, t2);
        MACLO(az, wza.w, t3); MACHI(ah, wha.w, t3);
      }
      az *= rsz;
      ah *= rsh;

      // ---- epilogue: ELU + bias + self + GRU step, all in f32 ----
      f16x2 sp = __builtin_bit_cast(f16x2, spd);
      float vz = az + bz; vz = vz > 0.f ? vz : __expf(vz) - 1.f;
      float vh = ah + bh; vh = vh > 0.f ? vh : __expf(vh) - 1.f;
      float zp = vz + (float)sp.x + hc;
      float tp = vh + (float)sp.y + hc;
      float zg = RCPF(1.f + __expf(-zp));                   // sigmoid
      float tg = 1.f - 2.f * RCPF(__expf(2.f * tp) + 1.f);  // tanh
      hc = zg * hc + (1.f - zg) * tg;
    }

    out[(size_t)node * 64 + ch] = (hc - bnm) * bns * bng + bnb;
  }
}

// ---------------------------------------------------------------------------
extern "C" void kernel_launch(void* const* d_in, const int* in_sizes, int n_in,
                              void* d_out, int out_size, void* d_ws, size_t ws_size,
                              hipStream_t stream) {
  (void)in_sizes; (void)n_in; (void)out_size; (void)ws_size;
  const float* X   = (const float*)d_in[0];
  const float* bm  = (const float*)d_in[1];
  const float* Wz  = (const float*)d_in[2];
  const float* Zb  = (const float*)d_in[3];
  const float* Wh  = (const float*)d_in[4];
  const float* Hb  = (const float*)d_in[5];
  const float* Wgz = (const float*)d_in[6];
  const float* a1z = (const float*)d_in[7];
  const float* a2z = (const float*)d_in[8];
  const float* bgz = (const float*)d_in[9];
  const float* Wgh = (const float*)d_in[10];
  const float* a1h = (const float*)d_in[11];
  const float* a2h = (const float*)d_in[12];
  const float* bgh = (const float*)d_in[13];
  const float* gam = (const float*)d_in[14];
  const float* bet = (const float*)d_in[15];
  const float* mu  = (const float*)d_in[16];
  const float* var = (const float*)d_in[17];
  float* out = (float*)d_out;

  char* p = (char*)d_ws;
  uint32_t* gbufF = (uint32_t*)p; p += (size_t)NR * 64 * sizeof(uint32_t);  // 25 MB
  uint32_t* gbufS = (uint32_t*)p; p += (size_t)NR * 64 * sizeof(uint32_t);  // 25 MB
  float*    fbuf  = (float*)p;    p += (size_t)NR * 16 * sizeof(float);     // 6 MB
  int*      adj   = (int*)p;      p += (size_t)NB * NN * MAXD * sizeof(int);// 2 MB
  int*      deg   = (int*)p;      p += (size_t)NB * NN * sizeof(int);       // 32 KB
  _Float16* W16   = (_Float16*)p; p += 272 * 64 * sizeof(_Float16);         // 34 KB
  float*    biasC = (float*)p;    p += 128 * sizeof(float);
  int*      ctr   = (int*)p;      p += 8 * sizeof(int);

  prep_w_k<<<dim3(68), dim3(256), 0, stream>>>(
      Wgz, Wgh, Wz, Wh, a1z, a2z, a1h, a2h, Zb, Hb, W16, biasC);
  build_adj_k<<<dim3(NB * NN / 4), dim3(256), 0, stream>>>(bm, adj, deg, ctr);
  mfma_gemm_k<<<dim3(NR / 64), dim3(256), 0, stream>>>(
      X, W16, biasC, gbufF, gbufS, fbuf);
  attn_gru_k<<<dim3(1024), dim3(256), 0, stream>>>(
      gbufF, gbufS, fbuf, adj, deg, bgz, bgh, gam, bet, mu, var, ctr, out);
}

// Round 6
// 367.009 us; speedup vs baseline: 1.1906x; 1.1906x over previous
//
#include <hip/hip_runtime.h>
#include <cstdint>
#include <cstddef>

// Problem constants (fixed by setup_inputs)
#define NB 4      // batch
#define NT 12     // timesteps
#define NN 2048   // nodes
#define NF 64     // in features
#define NH 4      // heads
#define ND 16     // head dim
#define NC 64     // out channels
#define MAXD 64   // max neighbors kept (Binomial(2047,16/2048): P(deg>64)~1e-19)
#define NR (NB * NT * NN)  // 98304 batched GEMM rows

typedef _Float16 f16x8 __attribute__((ext_vector_type(8)));
typedef _Float16 f16x2 __attribute__((ext_vector_type(2)));
typedef float f32x4 __attribute__((ext_vector_type(4)));

#define LR(v) ((v) >= 0.f ? (v) : 0.2f * (v))
#define RCPF(x) __builtin_amdgcn_rcpf(x)

// v_fma_mix_f32: acc += w * (f32)(f16 half of d).
#define MACLO(acc, w, d)                                                      \
  asm("v_fma_mix_f32 %0, %1, %2, %0 op_sel:[0,0,0] op_sel_hi:[0,1,0]"         \
      : "+v"(acc) : "v"(w), "v"(d))
#define MACHI(acc, w, d)                                                      \
  asm("v_fma_mix_f32 %0, %1, %2, %0 op_sel:[0,1,0] op_sel_hi:[0,1,0]"         \
      : "+v"(acc) : "v"(w), "v"(d))

// ---------------------------------------------------------------------------
// Build padded adjacency lists from the additive mask (0 / -1e9), one wave/row.
// Also zeroes the 8 per-XCD ticket counters used by attn_gru_k (runs before
// it on the same stream every graph replay).
__global__ __launch_bounds__(256) void build_adj_k(const float* __restrict__ bias,
                                                   int* __restrict__ adj,
                                                   int* __restrict__ deg,
                                                   int* __restrict__ ctr) {
  if (blockIdx.x < 8 && threadIdx.x == 0) ctr[blockIdx.x] = 0;
  int gtid = blockIdx.x * 256 + threadIdx.x;
  int wid = gtid >> 6;            // row id in [0, NB*NN)
  int lane = threadIdx.x & 63;
  if (wid >= NB * NN) return;
  const float* row = bias + (size_t)wid * NN;
  int* arow = adj + (size_t)wid * MAXD;
  int count = 0;
  for (int c0 = 0; c0 < NN; c0 += 64) {
    float v = __builtin_nontemporal_load(row + c0 + lane);  // 67 MB single-use
    bool e = (v > -1e8f);                       // edge iff mask == 0
    unsigned long long m = __ballot(e);
    int pre = __popcll(m & ((1ull << lane) - 1ull));
    if (e) {
      int pos = count + pre;
      if (pos < MAXD) arow[pos] = c0 + lane;
    }
    count += __popcll(m);
  }
  if (lane == 0) deg[wid] = count < MAXD ? count : MAXD;
}

// ---------------------------------------------------------------------------
// One-shot weight prep: fp16 W16[272][64] in B-fragment layout + biasC[128].
__global__ __launch_bounds__(256) void prep_w_k(
    const float* __restrict__ Wgz, const float* __restrict__ Wgh,
    const float* __restrict__ Wz,  const float* __restrict__ Wh,
    const float* __restrict__ a1z, const float* __restrict__ a2z,
    const float* __restrict__ a1h, const float* __restrict__ a2h,
    const float* __restrict__ Zb,  const float* __restrict__ Hb,
    _Float16* __restrict__ W16, float* __restrict__ biasC) {
  int idx = blockIdx.x * 256 + threadIdx.x;
  if (idx < 272 * 64) {
    int c = idx >> 6, k = idx & 63;
    float w;
    if (c < 64)       w = Wgz[((c >> 4) << 10) + (k << 4) + (c & 15)];
    else if (c < 128) { int q = c - 64; w = Wgh[((q >> 4) << 10) + (k << 4) + (q & 15)]; }
    else if (c < 192) w = Wz[(k << 6) + (c - 128)];
    else if (c < 256) w = Wh[(k << 6) + (c - 192)];
    else {
      int j = c - 256, h = j & 3;
      const float* Wg = (j & 4) ? Wgh : Wgz;
      const float* av = (j & 8) ? ((j & 4) ? a2h : a2z) : ((j & 4) ? a1h : a1z);
      float s = 0.f;
#pragma unroll
      for (int d = 0; d < 16; d++)
        s = fmaf(Wg[(h << 10) + (k << 4) + d], av[(h << 4) + d], s);
      w = s;
    }
    W16[idx] = (_Float16)w;
  }
  if (blockIdx.x == 0 && threadIdx.x < 128)
    biasC[threadIdx.x] =
        (threadIdx.x < 64) ? Zb[threadIdx.x] : Hb[threadIdx.x - 64];
}

// ---------------------------------------------------------------------------
// fp16 MFMA GEMM: [98304 x 64] @ [64 x 272], fp32 accumulate. (unchanged)
__global__ __launch_bounds__(256) void mfma_gemm_k(
    const float* __restrict__ X, const _Float16* __restrict__ W16,
    const float* __restrict__ biasC,
    uint32_t* __restrict__ gbufF, uint32_t* __restrict__ gbufS,
    float* __restrict__ fbuf) {
  __shared__ uint32_t tr[4][16 * 68];   // per-wave 16 rows x 64 cols (+pad)
  const int tid = threadIdx.x;
  const int wv = tid >> 6, lane = tid & 63;
  const int m = lane & 15, quad = lane >> 4;
  const unsigned rw = blockIdx.x * 64 + wv * 16;      // wave's row base
  uint32_t* tw = tr[wv];

  const float* xr = X + (size_t)(rw + m) * 64;
  float4 x0 = *(const float4*)(xr + quad * 8);
  float4 x1 = *(const float4*)(xr + quad * 8 + 4);
  float4 x2 = *(const float4*)(xr + 32 + quad * 8);
  float4 x3 = *(const float4*)(xr + 32 + quad * 8 + 4);
  f16x8 A0 = {(_Float16)x0.x, (_Float16)x0.y, (_Float16)x0.z, (_Float16)x0.w,
              (_Float16)x1.x, (_Float16)x1.y, (_Float16)x1.z, (_Float16)x1.w};
  f16x8 A1 = {(_Float16)x2.x, (_Float16)x2.y, (_Float16)x2.z, (_Float16)x2.w,
              (_Float16)x3.x, (_Float16)x3.y, (_Float16)x3.z, (_Float16)x3.w};

  float bzc[4], bhc[4];
#pragma unroll
  for (int j = 0; j < 4; j++) {
    bzc[j] = biasC[j * 16 + m];
    bhc[j] = biasC[64 + j * 16 + m];
  }
  const int rsub = lane >> 4, chk = lane & 15;   // readback: row-sub, chunk

  f32x4 zacc[4], zs[4];
#pragma unroll
  for (int ct = 0; ct < 17; ct++) {
    const _Float16* wp = W16 + (ct * 16 + m) * 64;
    f16x8 B0 = *(const f16x8*)(wp + quad * 8);
    f16x8 B1 = *(const f16x8*)(wp + 32 + quad * 8);
    f32x4 acc = {0.f, 0.f, 0.f, 0.f};
    acc = __builtin_amdgcn_mfma_f32_16x16x32_f16(A0, B0, acc, 0, 0, 0);
    acc = __builtin_amdgcn_mfma_f32_16x16x32_f16(A1, B1, acc, 0, 0, 0);
    // C-layout: row = quad*4 + r, col = ct*16 + m  [measured: learn_hip m89]
    if (ct < 4) {
      zacc[ct] = acc;                        // z-feat tiles, saved for pairing
    } else if (ct < 8) {
      const int j = ct - 4;                  // h-feat tile -> pack {z,h}
#pragma unroll
      for (int r = 0; r < 4; r++) {
        f16x2 pv = {(_Float16)zacc[j][r], (_Float16)acc[r]};
        tw[(quad * 4 + r) * 68 + j * 16 + m] = __builtin_bit_cast(uint32_t, pv);
      }
      if (ct == 7) {   // full-tile readback: 4 stores x (16 lanes = 256B row)
#pragma unroll
        for (int i = 0; i < 4; i++) {
          int row = i * 4 + rsub;
          uint4 v = *(const uint4*)&tw[row * 68 + chk * 4];
          *(uint4*)&gbufF[(size_t)(rw + row) * 64 + chk * 4] = v;
        }
      }
    } else if (ct < 12) {
#pragma unroll
      for (int r = 0; r < 4; r++) zs[ct - 8][r] = acc[r] + bzc[ct - 8];
    } else if (ct < 16) {
      const int j = ct - 12;
#pragma unroll
      for (int r = 0; r < 4; r++) {
        f16x2 pv = {(_Float16)zs[j][r], (_Float16)(acc[r] + bhc[j])};
        tw[(quad * 4 + r) * 68 + j * 16 + m] = __builtin_bit_cast(uint32_t, pv);
      }
      if (ct == 15) {
#pragma unroll
        for (int i = 0; i < 4; i++) {
          int row = i * 4 + rsub;
          uint4 v = *(const uint4*)&tw[row * 68 + chk * 4];
          *(uint4*)&gbufS[(size_t)(rw + row) * 64 + chk * 4] = v;
        }
      }
    } else {
      const unsigned rb = rw + quad * 4;
#pragma unroll
      for (int r = 0; r < 4; r++) fbuf[(size_t)(rb + r) * 16 + m] = acc[r];
    }
  }
}

// ---------------------------------------------------------------------------
// Fused attention + GRU, R6 = R3 loop body (known-good: 40 VGPR, no scratch)
// + per-XCD work-stealing tickets for load balance.
//  - Grid 1536 blocks (6144 waves; 6 blocks/CU). Waves pull nodes from their
//    XCD group's atomic counter (g = bid&7, nodes [g*1024,(g+1)*1024)):
//    greedy balance kills the degree-straggler tail that left R3's machine
//    40%-occupied on average (100% -> 0 decay). 1.33 nodes/wave average.
//  - R4's register-hoisted offset blocks REMOVED: they spilled to scratch
//    (R5: WRITE_SIZE 107 MB, VALUBusy 11%). Gather reads adjL from LDS,
//    8-wide batches, exactly as R3.
//  - Keeps: XCD batch affinity, cross-t feature prefetch, self pre-gate
//    prefetch, fma_mix MACs, cooperative row-sum reduce, f32 GRU + fused BN.
__global__ __launch_bounds__(256) void attn_gru_k(
    const uint32_t* __restrict__ gbufF, const uint32_t* __restrict__ gbufS,
    const float* __restrict__ fbuf,
    const int* __restrict__ adj, const int* __restrict__ deg,
    const float* __restrict__ bgz, const float* __restrict__ bgh,
    const float* __restrict__ gam, const float* __restrict__ bet,
    const float* __restrict__ mu, const float* __restrict__ var,
    int* __restrict__ ctr, float* __restrict__ out) {
  __shared__ int adjL[4][MAXD];
  __shared__ float wexp[4][8][68];      // stride 68 kills head-alias
  const int tid = threadIdx.x;
  const int lane = tid & 63;
  const int ws = tid >> 6;
  const int g = blockIdx.x & 7;         // XCD group; nodes [g*1024,(g+1)*1024)
  const int ch = lane, hh = lane >> 4;
  const int sr = lane & 7, ss = lane >> 3;   // sum-reduce: row, segment

  // Per-channel constants (node-independent, hoisted out of the ticket loop)
  const float bz = bgz[ch], bh = bgh[ch];
  const float bnm = mu[ch];
  const float bns = rsqrtf(var[ch] + 1e-3f);
  const float bng = gam[ch], bnb = bet[ch];

  int* ctrg = ctr + g;
  for (;;) {
    int tk = 0;
    if (lane == 0) tk = atomicAdd(ctrg, 1);
    tk = __shfl(tk, 0);
    if (tk >= NN * NB / 8) break;       // 1024 nodes per group
    const int node = g * (NN * NB / 8) + tk;
    const int b = node >> 11;
    const int nl = node & (NN - 1);
    const int dg = deg[node];
    const int myadj = (lane < dg) ? adj[node * MAXD + lane] : 0;
    adjL[ws][lane] = myadj;
    const int dgp = (dg + 3) & ~3;      // 4-granular pad

    // Re-zero wexp per node (dg varies between nodes): pad slots (>= dg)
    // stay 0 for every t (inert in both the row sums and the gather).
#pragma unroll
    for (int k = 0; k < 8; k++) wexp[ws][k][lane] = 0.f;

    // Rotating feature registers: f1 (own row, bcast) + f2 (lane's neighbor).
    float4 c1z, c1h, c2z, c2h;
    {
      const float* fb0 = fbuf + (size_t)(b * NT) * NN * 16;
      const float4* p0 = (const float4*)(fb0 + nl * 16);
      const float4* q0 = (const float4*)(fb0 + (size_t)myadj * 16);
      c1z = p0[0]; c1h = p0[1]; c2z = q0[2]; c2h = q0[3];
    }

    float hc = 0.f;
#pragma unroll 1
    for (int t = 0; t < NT; t++) {
      const unsigned rb = (unsigned)(b * NT + t) * NN;
      const uint32_t* gF = gbufF + (size_t)rb * 64;
      // self pre-gate dword: issue now, consumed in epilogue
      const uint32_t spd = gbufS[((size_t)rb + nl) * 64 + ch];

      // ---- phase 1: raw exp attention weights from prefetched regs ----
      float e0 = __expf(LR(c1z.x + c2z.x));
      float e1 = __expf(LR(c1z.y + c2z.y));
      float e2 = __expf(LR(c1z.z + c2z.z));
      float e3 = __expf(LR(c1z.w + c2z.w));
      float e4 = __expf(LR(c1h.x + c2h.x));
      float e5 = __expf(LR(c1h.y + c2h.y));
      float e6 = __expf(LR(c1h.z + c2h.z));
      float e7 = __expf(LR(c1h.w + c2h.w));
      if (lane < dg) {                    // masked: pad slots stay 0
        wexp[ws][0][lane] = e0;
        wexp[ws][1][lane] = e1;
        wexp[ws][2][lane] = e2;
        wexp[ws][3][lane] = e3;
        wexp[ws][4][lane] = e4;
        wexp[ws][5][lane] = e5;
        wexp[ws][6][lane] = e6;
        wexp[ws][7][lane] = e7;
      }

      // ---- issue t+1 feature prefetch (hidden under reduce+gather) ----
      if (t + 1 < NT) {
        const float* fbn = fbuf + ((size_t)rb + NN) * 16;
        const float4* pn = (const float4*)(fbn + nl * 16);
        const float4* qn = (const float4*)(fbn + (size_t)myadj * 16);
        c1z = pn[0]; c1h = pn[1]; c2z = qn[2]; c2h = qn[3];
      }

      // ---- phase 1.5: cooperative row sums (same-wave LDS ordering) ----
      float4 u0 = *(const float4*)&wexp[ws][sr][ss * 8];
      float4 u1 = *(const float4*)&wexp[ws][sr][ss * 8 + 4];
      float part = ((u0.x + u0.y) + (u0.z + u0.w)) +
                   ((u1.x + u1.y) + (u1.z + u1.w));
      part += __shfl_xor(part, 8);
      part += __shfl_xor(part, 16);
      part += __shfl_xor(part, 32);
      const float rsz = RCPF(__shfl(part, hh));
      const float rsh = RCPF(__shfl(part, 4 + hh));

      // ---- phase 2: 8-wide gather (8 loads in flight) + 4-wide rem ----
      float az = 0.f, ah = 0.f;
      const float* wz = wexp[ws][hh];
      const float* wh = wexp[ws][4 + hh];
      int mi = 0;
      for (; mi + 8 <= dgp; mi += 8) {
        int4 ma = *(const int4*)&adjL[ws][mi];
        int4 mb = *(const int4*)&adjL[ws][mi + 4];
        uint32_t d0 = gF[(ma.x << 6) + ch];
        uint32_t d1 = gF[(ma.y << 6) + ch];
        uint32_t d2 = gF[(ma.z << 6) + ch];
        uint32_t d3 = gF[(ma.w << 6) + ch];
        uint32_t d4 = gF[(mb.x << 6) + ch];
        uint32_t d5 = gF[(mb.y << 6) + ch];
        uint32_t d6 = gF[(mb.z << 6) + ch];
        uint32_t d7 = gF[(mb.w << 6) + ch];
        float4 wza = *(const float4*)&wz[mi];
        float4 wzb = *(const float4*)&wz[mi + 4];
        float4 wha = *(const float4*)&wh[mi];
        float4 whb = *(const float4*)&wh[mi + 4];
        MACLO(az, wza.x, d0); MACHI(ah, wha.x, d0);
        MACLO(az, wza.y, d1); MACHI(ah, wha.y, d1);
        MACLO(az, wza.z, d2); MACHI(ah, wha.z, d2);
        MACLO(az, wza.w, d3); MACHI(ah, wha.w, d3);
        MACLO(az, wzb.x, d4); MACHI(ah, whb.x, d4);
        MACLO(az, wzb.y, d5); MACHI(ah, whb.y, d5);
        MACLO(az, wzb.z, d6); MACHI(ah, whb.z, d6);
        MACLO(az, wzb.w, d7); MACHI(ah, whb.w, d7);
      }
      if (mi < dgp) {                    // dgp is 4-granular: exactly 4 left
        int4 ma = *(const int4*)&adjL[ws][mi];
        uint32_t d0 = gF[(ma.x << 6) + ch];
        uint32_t d1 = gF[(ma.y << 6) + ch];
        uint32_t d2 = gF[(ma.z << 6) + ch];
        uint32_t d3 = gF[(ma.w << 6) + ch];
        float4 wza = *(const float4*)&wz[mi];
        float4 wha = *(const float4*)&wh[mi];
        MACLO(az, wza.x, d0); MACHI(ah, wha.x, d0);
        MACLO(az, wza.y, d1); MACHI(ah, wha.y, d1);
        MACLO(az, wza.z, d2); MACHI(ah, wha.z, d2);
        MACLO(az, wza.w, d3); MACHI(ah, wha.w, d3);
      }
      az *= rsz;
      ah *= rsh;

      // ---- epilogue: ELU + bias + self + GRU step, all in f32 ----
      f16x2 sp = __builtin_bit_cast(f16x2, spd);
      float vz = az + bz; vz = vz > 0.f ? vz : __expf(vz) - 1.f;
      float vh = ah + bh; vh = vh > 0.f ? vh : __expf(vh) - 1.f;
      float zp = vz + (float)sp.x + hc;
      float tp = vh + (float)sp.y + hc;
      float zg = RCPF(1.f + __expf(-zp));                   // sigmoid
      float tg = 1.f - 2.f * RCPF(__expf(2.f * tp) + 1.f);  // tanh
      hc = zg * hc + (1.f - zg) * tg;
    }

    out[(size_t)node * 64 + ch] = (hc - bnm) * bns * bng + bnb;
  }
}

// ---------------------------------------------------------------------------
extern "C" void kernel_launch(void* const* d_in, const int* in_sizes, int n_in,
                              void* d_out, int out_size, void* d_ws, size_t ws_size,
                              hipStream_t stream) {
  (void)in_sizes; (void)n_in; (void)out_size; (void)ws_size;
  const float* X   = (const float*)d_in[0];
  const float* bm  = (const float*)d_in[1];
  const float* Wz  = (const float*)d_in[2];
  const float* Zb  = (const float*)d_in[3];
  const float* Wh  = (const float*)d_in[4];
  const float* Hb  = (const float*)d_in[5];
  const float* Wgz = (const float*)d_in[6];
  const float* a1z = (const float*)d_in[7];
  const float* a2z = (const float*)d_in[8];
  const float* bgz = (const float*)d_in[9];
  const float* Wgh = (const float*)d_in[10];
  const float* a1h = (const float*)d_in[11];
  const float* a2h = (const float*)d_in[12];
  const float* bgh = (const float*)d_in[13];
  const float* gam = (const float*)d_in[14];
  const float* bet = (const float*)d_in[15];
  const float* mu  = (const float*)d_in[16];
  const float* var = (const float*)d_in[17];
  float* out = (float*)d_out;

  char* p = (char*)d_ws;
  uint32_t* gbufF = (uint32_t*)p; p += (size_t)NR * 64 * sizeof(uint32_t);  // 25 MB
  uint32_t* gbufS = (uint32_t*)p; p += (size_t)NR * 64 * sizeof(uint32_t);  // 25 MB
  float*    fbuf  = (float*)p;    p += (size_t)NR * 16 * sizeof(float);     // 6 MB
  int*      adj   = (int*)p;      p += (size_t)NB * NN * MAXD * sizeof(int);// 2 MB
  int*      deg   = (int*)p;      p += (size_t)NB * NN * sizeof(int);       // 32 KB
  _Float16* W16   = (_Float16*)p; p += 272 * 64 * sizeof(_Float16);         // 34 KB
  float*    biasC = (float*)p;    p += 128 * sizeof(float);
  int*      ctr   = (int*)p;      p += 8 * sizeof(int);

  prep_w_k<<<dim3(68), dim3(256), 0, stream>>>(
      Wgz, Wgh, Wz, Wh, a1z, a2z, a1h, a2h, Zb, Hb, W16, biasC);
  build_adj_k<<<dim3(NB * NN / 4), dim3(256), 0, stream>>>(bm, adj, deg, ctr);
  mfma_gemm_k<<<dim3(NR / 64), dim3(256), 0, stream>>>(
      X, W16, biasC, gbufF, gbufS, fbuf);
  attn_gru_k<<<dim3(1536), dim3(256), 0, stream>>>(
      gbufF, gbufS, fbuf, adj, deg, bgz, bgh, gam, bet, mu, var, ctr, out);
}

// Round 7
// 245.930 us; speedup vs baseline: 1.7768x; 1.4923x over previous
//
#include <hip/hip_runtime.h>
#include <cstdint>
#include <cstddef>

// Problem constants (fixed by setup_inputs)
#define NB 4      // batch
#define NT 12     // timesteps
#define NN 2048   // nodes
#define NF 64     // in features
#define NH 4      // heads
#define ND 16     // head dim
#define NC 64     // out channels
#define MAXD 64   // max neighbors kept (Binomial(2047,16/2048): P(deg>64)~1e-19)
#define NR (NB * NT * NN)  // 98304 batched GEMM rows

// attn_gru_k stealing geometry
#define AG_BLOCKS 1536
#define WPG (AG_BLOCKS * 4 / 8)   // 768 waves per XCD group
#define NPG (NB * NN / 8)         // 1024 nodes per XCD group
#define CTR_STRIDE 32             // one counter per 128B line

typedef _Float16 f16x8 __attribute__((ext_vector_type(8)));
typedef _Float16 f16x2 __attribute__((ext_vector_type(2)));
typedef float f32x4 __attribute__((ext_vector_type(4)));

#define LR(v) ((v) >= 0.f ? (v) : 0.2f * (v))
#define RCPF(x) __builtin_amdgcn_rcpf(x)

// v_fma_mix_f32: acc += w * (f32)(f16 half of d).
#define MACLO(acc, w, d)                                                      \
  asm("v_fma_mix_f32 %0, %1, %2, %0 op_sel:[0,0,0] op_sel_hi:[0,1,0]"         \
      : "+v"(acc) : "v"(w), "v"(d))
#define MACHI(acc, w, d)                                                      \
  asm("v_fma_mix_f32 %0, %1, %2, %0 op_sel:[0,1,0] op_sel_hi:[0,1,0]"         \
      : "+v"(acc) : "v"(w), "v"(d))

// ---------------------------------------------------------------------------
// Build padded adjacency lists from the additive mask (0 / -1e9), one wave/row.
// Also inits the 8 padded per-XCD steal counters to WPG (static-first design:
// nodes [0,WPG) per group are claimed statically; stealing covers [WPG,NPG)).
__global__ __launch_bounds__(256) void build_adj_k(const float* __restrict__ bias,
                                                   int* __restrict__ adj,
                                                   int* __restrict__ deg,
                                                   int* __restrict__ ctr) {
  if (blockIdx.x == 0 && threadIdx.x < 8) ctr[threadIdx.x * CTR_STRIDE] = WPG;
  int gtid = blockIdx.x * 256 + threadIdx.x;
  int wid = gtid >> 6;            // row id in [0, NB*NN)
  int lane = threadIdx.x & 63;
  if (wid >= NB * NN) return;
  const float* row = bias + (size_t)wid * NN;
  int* arow = adj + (size_t)wid * MAXD;
  int count = 0;
  for (int c0 = 0; c0 < NN; c0 += 64) {
    float v = __builtin_nontemporal_load(row + c0 + lane);  // 67 MB single-use
    bool e = (v > -1e8f);                       // edge iff mask == 0
    unsigned long long m = __ballot(e);
    int pre = __popcll(m & ((1ull << lane) - 1ull));
    if (e) {
      int pos = count + pre;
      if (pos < MAXD) arow[pos] = c0 + lane;
    }
    count += __popcll(m);
  }
  if (lane == 0) deg[wid] = count < MAXD ? count : MAXD;
}

// ---------------------------------------------------------------------------
// One-shot weight prep: fp16 W16[272][64] in B-fragment layout + biasC[128].
__global__ __launch_bounds__(256) void prep_w_k(
    const float* __restrict__ Wgz, const float* __restrict__ Wgh,
    const float* __restrict__ Wz,  const float* __restrict__ Wh,
    const float* __restrict__ a1z, const float* __restrict__ a2z,
    const float* __restrict__ a1h, const float* __restrict__ a2h,
    const float* __restrict__ Zb,  const float* __restrict__ Hb,
    _Float16* __restrict__ W16, float* __restrict__ biasC) {
  int idx = blockIdx.x * 256 + threadIdx.x;
  if (idx < 272 * 64) {
    int c = idx >> 6, k = idx & 63;
    float w;
    if (c < 64)       w = Wgz[((c >> 4) << 10) + (k << 4) + (c & 15)];
    else if (c < 128) { int q = c - 64; w = Wgh[((q >> 4) << 10) + (k << 4) + (q & 15)]; }
    else if (c < 192) w = Wz[(k << 6) + (c - 128)];
    else if (c < 256) w = Wh[(k << 6) + (c - 192)];
    else {
      int j = c - 256, h = j & 3;
      const float* Wg = (j & 4) ? Wgh : Wgz;
      const float* av = (j & 8) ? ((j & 4) ? a2h : a2z) : ((j & 4) ? a1h : a1z);
      float s = 0.f;
#pragma unroll
      for (int d = 0; d < 16; d++)
        s = fmaf(Wg[(h << 10) + (k << 4) + d], av[(h << 4) + d], s);
      w = s;
    }
    W16[idx] = (_Float16)w;
  }
  if (blockIdx.x == 0 && threadIdx.x < 128)
    biasC[threadIdx.x] =
        (threadIdx.x < 64) ? Zb[threadIdx.x] : Hb[threadIdx.x - 64];
}

// ---------------------------------------------------------------------------
// fp16 MFMA GEMM: [98304 x 64] @ [64 x 272], fp32 accumulate. (unchanged)
__global__ __launch_bounds__(256) void mfma_gemm_k(
    const float* __restrict__ X, const _Float16* __restrict__ W16,
    const float* __restrict__ biasC,
    uint32_t* __restrict__ gbufF, uint32_t* __restrict__ gbufS,
    float* __restrict__ fbuf) {
  __shared__ uint32_t tr[4][16 * 68];   // per-wave 16 rows x 64 cols (+pad)
  const int tid = threadIdx.x;
  const int wv = tid >> 6, lane = tid & 63;
  const int m = lane & 15, quad = lane >> 4;
  const unsigned rw = blockIdx.x * 64 + wv * 16;      // wave's row base
  uint32_t* tw = tr[wv];

  const float* xr = X + (size_t)(rw + m) * 64;
  float4 x0 = *(const float4*)(xr + quad * 8);
  float4 x1 = *(const float4*)(xr + quad * 8 + 4);
  float4 x2 = *(const float4*)(xr + 32 + quad * 8);
  float4 x3 = *(const float4*)(xr + 32 + quad * 8 + 4);
  f16x8 A0 = {(_Float16)x0.x, (_Float16)x0.y, (_Float16)x0.z, (_Float16)x0.w,
              (_Float16)x1.x, (_Float16)x1.y, (_Float16)x1.z, (_Float16)x1.w};
  f16x8 A1 = {(_Float16)x2.x, (_Float16)x2.y, (_Float16)x2.z, (_Float16)x2.w,
              (_Float16)x3.x, (_Float16)x3.y, (_Float16)x3.z, (_Float16)x3.w};

  float bzc[4], bhc[4];
#pragma unroll
  for (int j = 0; j < 4; j++) {
    bzc[j] = biasC[j * 16 + m];
    bhc[j] = biasC[64 + j * 16 + m];
  }
  const int rsub = lane >> 4, chk = lane & 15;   // readback: row-sub, chunk

  f32x4 zacc[4], zs[4];
#pragma unroll
  for (int ct = 0; ct < 17; ct++) {
    const _Float16* wp = W16 + (ct * 16 + m) * 64;
    f16x8 B0 = *(const f16x8*)(wp + quad * 8);
    f16x8 B1 = *(const f16x8*)(wp + 32 + quad * 8);
    f32x4 acc = {0.f, 0.f, 0.f, 0.f};
    acc = __builtin_amdgcn_mfma_f32_16x16x32_f16(A0, B0, acc, 0, 0, 0);
    acc = __builtin_amdgcn_mfma_f32_16x16x32_f16(A1, B1, acc, 0, 0, 0);
    // C-layout: row = quad*4 + r, col = ct*16 + m  [measured: learn_hip m89]
    if (ct < 4) {
      zacc[ct] = acc;                        // z-feat tiles, saved for pairing
    } else if (ct < 8) {
      const int j = ct - 4;                  // h-feat tile -> pack {z,h}
#pragma unroll
      for (int r = 0; r < 4; r++) {
        f16x2 pv = {(_Float16)zacc[j][r], (_Float16)acc[r]};
        tw[(quad * 4 + r) * 68 + j * 16 + m] = __builtin_bit_cast(uint32_t, pv);
      }
      if (ct == 7) {   // full-tile readback: 4 stores x (16 lanes = 256B row)
#pragma unroll
        for (int i = 0; i < 4; i++) {
          int row = i * 4 + rsub;
          uint4 v = *(const uint4*)&tw[row * 68 + chk * 4];
          *(uint4*)&gbufF[(size_t)(rw + row) * 64 + chk * 4] = v;
        }
      }
    } else if (ct < 12) {
#pragma unroll
      for (int r = 0; r < 4; r++) zs[ct - 8][r] = acc[r] + bzc[ct - 8];
    } else if (ct < 16) {
      const int j = ct - 12;
#pragma unroll
      for (int r = 0; r < 4; r++) {
        f16x2 pv = {(_Float16)zs[j][r], (_Float16)(acc[r] + bhc[j])};
        tw[(quad * 4 + r) * 68 + j * 16 + m] = __builtin_bit_cast(uint32_t, pv);
      }
      if (ct == 15) {
#pragma unroll
        for (int i = 0; i < 4; i++) {
          int row = i * 4 + rsub;
          uint4 v = *(const uint4*)&tw[row * 68 + chk * 4];
          *(uint4*)&gbufS[(size_t)(rw + row) * 64 + chk * 4] = v;
        }
      }
    } else {
      const unsigned rb = rw + quad * 4;
#pragma unroll
      for (int r = 0; r < 4; r++) fbuf[(size_t)(rb + r) * 16 + m] = acc[r];
    }
  }
}

// ---------------------------------------------------------------------------
// Fused attention + GRU, R7 = R3 loop body (known-good) + low-contention
// work distribution:
//  - Static first node: wave's first node = its group-local wave id (0..767).
//    No atomic for the first 6144 nodes -> no startup burst.
//  - Stealing only for nodes [768,1024) per group, via per-XCD counters
//    PADDED to one per 128B line (R6's single-line layout serialized all
//    14336 device-scope atomics at the coherence point: VALUBusy 61->21%,
//    +124 us). Now 8192 atomics spread over 8 lines and over time.
//  - Grid 1536 blocks (6144 waves, 24/CU): balanced T ~ 8192*mean/6144
//    instead of R3's straggler bound.
__global__ __launch_bounds__(256) void attn_gru_k(
    const uint32_t* __restrict__ gbufF, const uint32_t* __restrict__ gbufS,
    const float* __restrict__ fbuf,
    const int* __restrict__ adj, const int* __restrict__ deg,
    const float* __restrict__ bgz, const float* __restrict__ bgh,
    const float* __restrict__ gam, const float* __restrict__ bet,
    const float* __restrict__ mu, const float* __restrict__ var,
    int* __restrict__ ctr, float* __restrict__ out) {
  __shared__ int adjL[4][MAXD];
  __shared__ float wexp[4][8][68];      // stride 68 kills head-alias
  const int tid = threadIdx.x;
  const int lane = tid & 63;
  const int ws = tid >> 6;
  const int g = blockIdx.x & 7;         // XCD group; nodes [g*NPG,(g+1)*NPG)
  const int gwav = (blockIdx.x >> 3) * 4 + ws;   // group-local wave id 0..767
  const int ch = lane, hh = lane >> 4;
  const int sr = lane & 7, ss = lane >> 3;   // sum-reduce: row, segment

  // Per-channel constants (node-independent, hoisted out of the node loop)
  const float bz = bgz[ch], bh = bgh[ch];
  const float bnm = mu[ch];
  const float bns = rsqrtf(var[ch] + 1e-3f);
  const float bng = gam[ch], bnb = bet[ch];

  int* ctrg = ctr + g * CTR_STRIDE;
  int tk = gwav;                        // static first node (no atomic)
  for (;;) {
    const int node = g * NPG + tk;
    const int b = node >> 11;
    const int nl = node & (NN - 1);
    const int dg = deg[node];
    const int myadj = (lane < dg) ? adj[node * MAXD + lane] : 0;
    adjL[ws][lane] = myadj;
    const int dgp = (dg + 3) & ~3;      // 4-granular pad

    // Re-zero wexp per node (dg varies between nodes): pad slots (>= dg)
    // stay 0 for every t (inert in both the row sums and the gather).
#pragma unroll
    for (int k = 0; k < 8; k++) wexp[ws][k][lane] = 0.f;

    // Rotating feature registers: f1 (own row, bcast) + f2 (lane's neighbor).
    float4 c1z, c1h, c2z, c2h;
    {
      const float* fb0 = fbuf + (size_t)(b * NT) * NN * 16;
      const float4* p0 = (const float4*)(fb0 + nl * 16);
      const float4* q0 = (const float4*)(fb0 + (size_t)myadj * 16);
      c1z = p0[0]; c1h = p0[1]; c2z = q0[2]; c2h = q0[3];
    }

    float hc = 0.f;
#pragma unroll 1
    for (int t = 0; t < NT; t++) {
      const unsigned rb = (unsigned)(b * NT + t) * NN;
      const uint32_t* gF = gbufF + (size_t)rb * 64;
      // self pre-gate dword: issue now, consumed in epilogue
      const uint32_t spd = gbufS[((size_t)rb + nl) * 64 + ch];

      // ---- phase 1: raw exp attention weights from prefetched regs ----
      float e0 = __expf(LR(c1z.x + c2z.x));
      float e1 = __expf(LR(c1z.y + c2z.y));
      float e2 = __expf(LR(c1z.z + c2z.z));
      float e3 = __expf(LR(c1z.w + c2z.w));
      float e4 = __expf(LR(c1h.x + c2h.x));
      float e5 = __expf(LR(c1h.y + c2h.y));
      float e6 = __expf(LR(c1h.z + c2h.z));
      float e7 = __expf(LR(c1h.w + c2h.w));
      if (lane < dg) {                    // masked: pad slots stay 0
        wexp[ws][0][lane] = e0;
        wexp[ws][1][lane] = e1;
        wexp[ws][2][lane] = e2;
        wexp[ws][3][lane] = e3;
        wexp[ws][4][lane] = e4;
        wexp[ws][5][lane] = e5;
        wexp[ws][6][lane] = e6;
        wexp[ws][7][lane] = e7;
      }

      // ---- issue t+1 feature prefetch (hidden under reduce+gather) ----
      if (t + 1 < NT) {
        const float* fbn = fbuf + ((size_t)rb + NN) * 16;
        const float4* pn = (const float4*)(fbn + nl * 16);
        const float4* qn = (const float4*)(fbn + (size_t)myadj * 16);
        c1z = pn[0]; c1h = pn[1]; c2z = qn[2]; c2h = qn[3];
      }

      // ---- phase 1.5: cooperative row sums (same-wave LDS ordering) ----
      float4 u0 = *(const float4*)&wexp[ws][sr][ss * 8];
      float4 u1 = *(const float4*)&wexp[ws][sr][ss * 8 + 4];
      float part = ((u0.x + u0.y) + (u0.z + u0.w)) +
                   ((u1.x + u1.y) + (u1.z + u1.w));
      part += __shfl_xor(part, 8);
      part += __shfl_xor(part, 16);
      part += __shfl_xor(part, 32);
      const float rsz = RCPF(__shfl(part, hh));
      const float rsh = RCPF(__shfl(part, 4 + hh));

      // ---- phase 2: 8-wide gather (8 loads in flight) + 4-wide rem ----
      float az = 0.f, ah = 0.f;
      const float* wz = wexp[ws][hh];
      const float* wh = wexp[ws][4 + hh];
      int mi = 0;
      for (; mi + 8 <= dgp; mi += 8) {
        int4 ma = *(const int4*)&adjL[ws][mi];
        int4 mb = *(const int4*)&adjL[ws][mi + 4];
        uint32_t d0 = gF[(ma.x << 6) + ch];
        uint32_t d1 = gF[(ma.y << 6) + ch];
        uint32_t d2 = gF[(ma.z << 6) + ch];
        uint32_t d3 = gF[(ma.w << 6) + ch];
        uint32_t d4 = gF[(mb.x << 6) + ch];
        uint32_t d5 = gF[(mb.y << 6) + ch];
        uint32_t d6 = gF[(mb.z << 6) + ch];
        uint32_t d7 = gF[(mb.w << 6) + ch];
        float4 wza = *(const float4*)&wz[mi];
        float4 wzb = *(const float4*)&wz[mi + 4];
        float4 wha = *(const float4*)&wh[mi];
        float4 whb = *(const float4*)&wh[mi + 4];
        MACLO(az, wza.x, d0); MACHI(ah, wha.x, d0);
        MACLO(az, wza.y, d1); MACHI(ah, wha.y, d1);
        MACLO(az, wza.z, d2); MACHI(ah, wha.z, d2);
        MACLO(az, wza.w, d3); MACHI(ah, wha.w, d3);
        MACLO(az, wzb.x, d4); MACHI(ah, whb.x, d4);
        MACLO(az, wzb.y, d5); MACHI(ah, whb.y, d5);
        MACLO(az, wzb.z, d6); MACHI(ah, whb.z, d6);
        MACLO(az, wzb.w, d7); MACHI(ah, whb.w, d7);
      }
      if (mi < dgp) {                    // dgp is 4-granular: exactly 4 left
        int4 ma = *(const int4*)&adjL[ws][mi];
        uint32_t d0 = gF[(ma.x << 6) + ch];
        uint32_t d1 = gF[(ma.y << 6) + ch];
        uint32_t d2 = gF[(ma.z << 6) + ch];
        uint32_t d3 = gF[(ma.w << 6) + ch];
        float4 wza = *(const float4*)&wz[mi];
        float4 wha = *(const float4*)&wh[mi];
        MACLO(az, wza.x, d0); MACHI(ah, wha.x, d0);
        MACLO(az, wza.y, d1); MACHI(ah, wha.y, d1);
        MACLO(az, wza.z, d2); MACHI(ah, wha.z, d2);
        MACLO(az, wza.w, d3); MACHI(ah, wha.w, d3);
      }
      az *= rsz;
      ah *= rsh;

      // ---- epilogue: ELU + bias + self + GRU step, all in f32 ----
      f16x2 sp = __builtin_bit_cast(f16x2, spd);
      float vz = az + bz; vz = vz > 0.f ? vz : __expf(vz) - 1.f;
      float vh = ah + bh; vh = vh > 0.f ? vh : __expf(vh) - 1.f;
      float zp = vz + (float)sp.x + hc;
      float tp = vh + (float)sp.y + hc;
      float zg = RCPF(1.f + __expf(-zp));                   // sigmoid
      float tg = 1.f - 2.f * RCPF(__expf(2.f * tp) + 1.f);  // tanh
      hc = zg * hc + (1.f - zg) * tg;
    }

    out[(size_t)node * 64 + ch] = (hc - bnm) * bns * bng + bnb;

    // ---- steal next node (only the 256/group tail nodes hit the atomic) ----
    if (lane == 0) tk = atomicAdd(ctrg, 1);
    tk = __shfl(tk, 0);
    if (tk >= NPG) break;
  }
}

// ---------------------------------------------------------------------------
extern "C" void kernel_launch(void* const* d_in, const int* in_sizes, int n_in,
                              void* d_out, int out_size, void* d_ws, size_t ws_size,
                              hipStream_t stream) {
  (void)in_sizes; (void)n_in; (void)out_size; (void)ws_size;
  const float* X   = (const float*)d_in[0];
  const float* bm  = (const float*)d_in[1];
  const float* Wz  = (const float*)d_in[2];
  const float* Zb  = (const float*)d_in[3];
  const float* Wh  = (const float*)d_in[4];
  const float* Hb  = (const float*)d_in[5];
  const float* Wgz = (const float*)d_in[6];
  const float* a1z = (const float*)d_in[7];
  const float* a2z = (const float*)d_in[8];
  const float* bgz = (const float*)d_in[9];
  const float* Wgh = (const float*)d_in[10];
  const float* a1h = (const float*)d_in[11];
  const float* a2h = (const float*)d_in[12];
  const float* bgh = (const float*)d_in[13];
  const float* gam = (const float*)d_in[14];
  const float* bet = (const float*)d_in[15];
  const float* mu  = (const float*)d_in[16];
  const float* var = (const float*)d_in[17];
  float* out = (float*)d_out;

  char* p = (char*)d_ws;
  uint32_t* gbufF = (uint32_t*)p; p += (size_t)NR * 64 * sizeof(uint32_t);  // 25 MB
  uint32_t* gbufS = (uint32_t*)p; p += (size_t)NR * 64 * sizeof(uint32_t);  // 25 MB
  float*    fbuf  = (float*)p;    p += (size_t)NR * 16 * sizeof(float);     // 6 MB
  int*      adj   = (int*)p;      p += (size_t)NB * NN * MAXD * sizeof(int);// 2 MB
  int*      deg   = (int*)p;      p += (size_t)NB * NN * sizeof(int);       // 32 KB
  _Float16* W16   = (_Float16*)p; p += 272 * 64 * sizeof(_Float16);         // 34 KB
  float*    biasC = (float*)p;    p += 128 * sizeof(float);
  int*      ctr   = (int*)p;      p += 8 * CTR_STRIDE * sizeof(int);        // 1 KB

  prep_w_k<<<dim3(68), dim3(256), 0, stream>>>(
      Wgz, Wgh, Wz, Wh, a1z, a2z, a1h, a2h, Zb, Hb, W16, biasC);
  build_adj_k<<<dim3(NB * NN / 4), dim3(256), 0, stream>>>(bm, adj, deg, ctr);
  mfma_gemm_k<<<dim3(NR / 64), dim3(256), 0, stream>>>(
      X, W16, biasC, gbufF, gbufS, fbuf);
  attn_gru_k<<<dim3(AG_BLOCKS), dim3(256), 0, stream>>>(
      gbufF, gbufS, fbuf, adj, deg, bgz, bgh, gam, bet, mu, var, ctr, out);
}

// Round 8
// 240.831 us; speedup vs baseline: 1.8144x; 1.0212x over previous
//
#include <hip/hip_runtime.h>
#include <cstdint>
#include <cstddef>

// Problem constants (fixed by setup_inputs)
#define NB 4      // batch
#define NT 12     // timesteps
#define NN 2048   // nodes
#define NF 64     // in features
#define NH 4      // heads
#define ND 16     // head dim
#define NC 64     // out channels
#define MAXD 64   // max neighbors kept (Binomial(2047,16/2048): P(deg>64)~1e-19)
#define NR (NB * NT * NN)  // 98304 batched GEMM rows

typedef _Float16 f16x8 __attribute__((ext_vector_type(8)));
typedef _Float16 f16x2 __attribute__((ext_vector_type(2)));
typedef float f32x4 __attribute__((ext_vector_type(4)));

// LeakyReLU 0.2: max(v, 0.2v) is exact for both signs (2 VALU: mul+max)
#define LR(v) fmaxf((v), 0.2f * (v))
#define RCPF(x) __builtin_amdgcn_rcpf(x)

// v_fma_mix_f32: acc += w * (f32)(f16 half of d).
#define MACLO(acc, w, d)                                                      \
  asm("v_fma_mix_f32 %0, %1, %2, %0 op_sel:[0,0,0] op_sel_hi:[0,1,0]"         \
      : "+v"(acc) : "v"(w), "v"(d))
#define MACHI(acc, w, d)                                                      \
  asm("v_fma_mix_f32 %0, %1, %2, %0 op_sel:[0,1,0] op_sel_hi:[0,1,0]"         \
      : "+v"(acc) : "v"(w), "v"(d))

// ---------------------------------------------------------------------------
// Build padded adjacency lists from the additive mask (0 / -1e9), one wave/row.
__global__ __launch_bounds__(256) void build_adj_k(const float* __restrict__ bias,
                                                   int* __restrict__ adj,
                                                   int* __restrict__ deg) {
  int gtid = blockIdx.x * 256 + threadIdx.x;
  int wid = gtid >> 6;            // row id in [0, NB*NN)
  int lane = threadIdx.x & 63;
  if (wid >= NB * NN) return;
  const float* row = bias + (size_t)wid * NN;
  int* arow = adj + (size_t)wid * MAXD;
  int count = 0;
  for (int c0 = 0; c0 < NN; c0 += 64) {
    float v = __builtin_nontemporal_load(row + c0 + lane);  // 67 MB single-use
    bool e = (v > -1e8f);                       // edge iff mask == 0
    unsigned long long m = __ballot(e);
    int pre = __popcll(m & ((1ull << lane) - 1ull));
    if (e) {
      int pos = count + pre;
      if (pos < MAXD) arow[pos] = c0 + lane;
    }
    count += __popcll(m);
  }
  if (lane == 0) deg[wid] = count < MAXD ? count : MAXD;
}

// ---------------------------------------------------------------------------
// One-shot weight prep: fp16 W16[272][64] in B-fragment layout + biasC[128].
__global__ __launch_bounds__(256) void prep_w_k(
    const float* __restrict__ Wgz, const float* __restrict__ Wgh,
    const float* __restrict__ Wz,  const float* __restrict__ Wh,
    const float* __restrict__ a1z, const float* __restrict__ a2z,
    const float* __restrict__ a1h, const float* __restrict__ a2h,
    const float* __restrict__ Zb,  const float* __restrict__ Hb,
    _Float16* __restrict__ W16, float* __restrict__ biasC) {
  int idx = blockIdx.x * 256 + threadIdx.x;
  if (idx < 272 * 64) {
    int c = idx >> 6, k = idx & 63;
    float w;
    if (c < 64)       w = Wgz[((c >> 4) << 10) + (k << 4) + (c & 15)];
    else if (c < 128) { int q = c - 64; w = Wgh[((q >> 4) << 10) + (k << 4) + (q & 15)]; }
    else if (c < 192) w = Wz[(k << 6) + (c - 128)];
    else if (c < 256) w = Wh[(k << 6) + (c - 192)];
    else {
      int j = c - 256, h = j & 3;
      const float* Wg = (j & 4) ? Wgh : Wgz;
      const float* av = (j & 8) ? ((j & 4) ? a2h : a2z) : ((j & 4) ? a1h : a1z);
      float s = 0.f;
#pragma unroll
      for (int d = 0; d < 16; d++)
        s = fmaf(Wg[(h << 10) + (k << 4) + d], av[(h << 4) + d], s);
      w = s;
    }
    W16[idx] = (_Float16)w;
  }
  if (blockIdx.x == 0 && threadIdx.x < 128)
    biasC[threadIdx.x] =
        (threadIdx.x < 64) ? Zb[threadIdx.x] : Hb[threadIdx.x - 64];
}

// ---------------------------------------------------------------------------
// fp16 MFMA GEMM: [98304 x 64] @ [64 x 272], fp32 accumulate. (unchanged)
__global__ __launch_bounds__(256) void mfma_gemm_k(
    const float* __restrict__ X, const _Float16* __restrict__ W16,
    const float* __restrict__ biasC,
    uint32_t* __restrict__ gbufF, uint32_t* __restrict__ gbufS,
    float* __restrict__ fbuf) {
  __shared__ uint32_t tr[4][16 * 68];   // per-wave 16 rows x 64 cols (+pad)
  const int tid = threadIdx.x;
  const int wv = tid >> 6, lane = tid & 63;
  const int m = lane & 15, quad = lane >> 4;
  const unsigned rw = blockIdx.x * 64 + wv * 16;      // wave's row base
  uint32_t* tw = tr[wv];

  const float* xr = X + (size_t)(rw + m) * 64;
  float4 x0 = *(const float4*)(xr + quad * 8);
  float4 x1 = *(const float4*)(xr + quad * 8 + 4);
  float4 x2 = *(const float4*)(xr + 32 + quad * 8);
  float4 x3 = *(const float4*)(xr + 32 + quad * 8 + 4);
  f16x8 A0 = {(_Float16)x0.x, (_Float16)x0.y, (_Float16)x0.z, (_Float16)x0.w,
              (_Float16)x1.x, (_Float16)x1.y, (_Float16)x1.z, (_Float16)x1.w};
  f16x8 A1 = {(_Float16)x2.x, (_Float16)x2.y, (_Float16)x2.z, (_Float16)x2.w,
              (_Float16)x3.x, (_Float16)x3.y, (_Float16)x3.z, (_Float16)x3.w};

  float bzc[4], bhc[4];
#pragma unroll
  for (int j = 0; j < 4; j++) {
    bzc[j] = biasC[j * 16 + m];
    bhc[j] = biasC[64 + j * 16 + m];
  }
  const int rsub = lane >> 4, chk = lane & 15;   // readback: row-sub, chunk

  f32x4 zacc[4], zs[4];
#pragma unroll
  for (int ct = 0; ct < 17; ct++) {
    const _Float16* wp = W16 + (ct * 16 + m) * 64;
    f16x8 B0 = *(const f16x8*)(wp + quad * 8);
    f16x8 B1 = *(const f16x8*)(wp + 32 + quad * 8);
    f32x4 acc = {0.f, 0.f, 0.f, 0.f};
    acc = __builtin_amdgcn_mfma_f32_16x16x32_f16(A0, B0, acc, 0, 0, 0);
    acc = __builtin_amdgcn_mfma_f32_16x16x32_f16(A1, B1, acc, 0, 0, 0);
    // C-layout: row = quad*4 + r, col = ct*16 + m  [measured: learn_hip m89]
    if (ct < 4) {
      zacc[ct] = acc;                        // z-feat tiles, saved for pairing
    } else if (ct < 8) {
      const int j = ct - 4;                  // h-feat tile -> pack {z,h}
#pragma unroll
      for (int r = 0; r < 4; r++) {
        f16x2 pv = {(_Float16)zacc[j][r], (_Float16)acc[r]};
        tw[(quad * 4 + r) * 68 + j * 16 + m] = __builtin_bit_cast(uint32_t, pv);
      }
      if (ct == 7) {   // full-tile readback: 4 stores x (16 lanes = 256B row)
#pragma unroll
        for (int i = 0; i < 4; i++) {
          int row = i * 4 + rsub;
          uint4 v = *(const uint4*)&tw[row * 68 + chk * 4];
          *(uint4*)&gbufF[(size_t)(rw + row) * 64 + chk * 4] = v;
        }
      }
    } else if (ct < 12) {
#pragma unroll
      for (int r = 0; r < 4; r++) zs[ct - 8][r] = acc[r] + bzc[ct - 8];
    } else if (ct < 16) {
      const int j = ct - 12;
#pragma unroll
      for (int r = 0; r < 4; r++) {
        f16x2 pv = {(_Float16)zs[j][r], (_Float16)(acc[r] + bhc[j])};
        tw[(quad * 4 + r) * 68 + j * 16 + m] = __builtin_bit_cast(uint32_t, pv);
      }
      if (ct == 15) {
#pragma unroll
        for (int i = 0; i < 4; i++) {
          int row = i * 4 + rsub;
          uint4 v = *(const uint4*)&tw[row * 68 + chk * 4];
          *(uint4*)&gbufS[(size_t)(rw + row) * 64 + chk * 4] = v;
        }
      }
    } else {
      const unsigned rb = rw + quad * 4;
#pragma unroll
      for (int r = 0; r < 4; r++) fbuf[(size_t)(rb + r) * 16 + m] = acc[r];
    }
  }
}

// ---------------------------------------------------------------------------
// Attention, R8: UNFUSED (node,t) grid — back to R0's high-parallelism
// structure (98304 work items, 24576 waves: no straggler/quantization bound,
// measured 71.8% occupancy / 93% VALUBusy) with the R2/R3-verified VALU cuts
// applied:
//  - cooperative row-sum reduce (replaces ~26 in-loop adds/lane)
//  - v_fma_mix gather MACs (no cvt, 2 VALU/neighbor for both gates)
//  - 4-granular degree padding (8-wide main + 4-wide remainder)
//  - adjacency pre-shifted <<6 in LDS: gbuf row = idx*64 dwords and fbuf row
//    = idx*64 bytes, so gather index = ma.x + ch (kills 1 shl per load)
//  - LR via fmaxf(v, 0.2v) (2 ops vs 3)
//  - self pre-gate dword issued at wave start, consumed in epilogue
// Grid (node-groups, t), x fastest: co-resident blocks share one t-slab
// (gF+gS+fbuf = 1.15 MB -> L2-resident, R0-measured FETCH 125 MB).
// Output abuf: f16-packed {zpre, hpre} for the GRU chain.
__global__ __launch_bounds__(256) void attn_k(
    const uint32_t* __restrict__ gbufF, const uint32_t* __restrict__ gbufS,
    const float* __restrict__ fbuf,
    const int* __restrict__ adj, const int* __restrict__ deg,
    const float* __restrict__ bgz, const float* __restrict__ bgh,
    uint32_t* __restrict__ abuf) {
  __shared__ int adjS[4][MAXD];         // pre-shifted neighbor offsets (<<6)
  __shared__ float wexp[4][8][68];      // stride 68 kills head-alias
  const int tid = threadIdx.x;
  const int lane = tid & 63;
  const int ws = tid >> 6;
  const int node = blockIdx.x * 4 + ws;
  const int t = blockIdx.y;
  const int b = node >> 11;
  const int nl = node & (NN - 1);
  const int dg = deg[node];
  adjS[ws][lane] = (lane < dg) ? (adj[node * MAXD + lane] << 6) : 0;
  const int dgp = (dg + 3) & ~3;        // 4-granular pad
  const int ch = lane, hh = lane >> 4;
  const int sr = lane & 7, ss = lane >> 3;   // sum-reduce: row, segment

  const unsigned rb = (unsigned)(b * NT + t) * NN;
  const float* fb = fbuf + (size_t)rb * 16;
  const uint32_t* gF = gbufF + (size_t)rb * 64;
  // self pre-gate dword: issue now, consumed in epilogue
  const uint32_t spd = gbufS[((size_t)rb + nl) * 64 + ch];

  // ---- phase 1: raw exp attention weights (lane = neighbor slot) ----
  {
    const float4* p = (const float4*)(fb + nl * 16);
    float4 f1z = p[0], f1h = p[1];
    if (lane < dg) {                    // exec-masked: inactive lanes load 0 B
      const float4* q =
          (const float4*)((const char*)fb + (size_t)(unsigned)adjS[ws][lane]);
      float4 f2z = q[2], f2h = q[3];
      wexp[ws][0][lane] = __expf(LR(f1z.x + f2z.x));
      wexp[ws][1][lane] = __expf(LR(f1z.y + f2z.y));
      wexp[ws][2][lane] = __expf(LR(f1z.z + f2z.z));
      wexp[ws][3][lane] = __expf(LR(f1z.w + f2z.w));
      wexp[ws][4][lane] = __expf(LR(f1h.x + f2h.x));
      wexp[ws][5][lane] = __expf(LR(f1h.y + f2h.y));
      wexp[ws][6][lane] = __expf(LR(f1h.z + f2h.z));
      wexp[ws][7][lane] = __expf(LR(f1h.w + f2h.w));
    } else {
#pragma unroll
      for (int k = 0; k < 8; k++) wexp[ws][k][lane] = 0.f;
    }
  }

  // ---- phase 1.5: cooperative row sums (same-wave LDS ordering) ----
  // lane l sums 8 values of row (l&7), segment (l>>3); butterfly over the
  // 8 segment lanes; lane r then holds sum of row r (replicated).
  float4 u0 = *(const float4*)&wexp[ws][sr][ss * 8];
  float4 u1 = *(const float4*)&wexp[ws][sr][ss * 8 + 4];
  float part = ((u0.x + u0.y) + (u0.z + u0.w)) +
               ((u1.x + u1.y) + (u1.z + u1.w));
  part += __shfl_xor(part, 8);
  part += __shfl_xor(part, 16);
  part += __shfl_xor(part, 32);
  const float rsz = RCPF(__shfl(part, hh));       // row hh lives in lane hh
  const float rsh = RCPF(__shfl(part, 4 + hh));

  // ---- phase 2: 8-wide gather (8 loads in flight) + 4-wide remainder ----
  float az = 0.f, ah = 0.f;
  const float* wz = wexp[ws][hh];
  const float* wh = wexp[ws][4 + hh];
  int mi = 0;
  for (; mi + 8 <= dgp; mi += 8) {
    int4 ma = *(const int4*)&adjS[ws][mi];
    int4 mb = *(const int4*)&adjS[ws][mi + 4];
    uint32_t d0 = gF[ma.x + ch];
    uint32_t d1 = gF[ma.y + ch];
    uint32_t d2 = gF[ma.z + ch];
    uint32_t d3 = gF[ma.w + ch];
    uint32_t d4 = gF[mb.x + ch];
    uint32_t d5 = gF[mb.y + ch];
    uint32_t d6 = gF[mb.z + ch];
    uint32_t d7 = gF[mb.w + ch];
    float4 wza = *(const float4*)&wz[mi];
    float4 wzb = *(const float4*)&wz[mi + 4];
    float4 wha = *(const float4*)&wh[mi];
    float4 whb = *(const float4*)&wh[mi + 4];
    MACLO(az, wza.x, d0); MACHI(ah, wha.x, d0);
    MACLO(az, wza.y, d1); MACHI(ah, wha.y, d1);
    MACLO(az, wza.z, d2); MACHI(ah, wha.z, d2);
    MACLO(az, wza.w, d3); MACHI(ah, wha.w, d3);
    MACLO(az, wzb.x, d4); MACHI(ah, whb.x, d4);
    MACLO(az, wzb.y, d5); MACHI(ah, whb.y, d5);
    MACLO(az, wzb.z, d6); MACHI(ah, whb.z, d6);
    MACLO(az, wzb.w, d7); MACHI(ah, whb.w, d7);
  }
  if (mi < dgp) {                      // dgp is 4-granular: exactly 4 left
    int4 ma = *(const int4*)&adjS[ws][mi];
    uint32_t d0 = gF[ma.x + ch];
    uint32_t d1 = gF[ma.y + ch];
    uint32_t d2 = gF[ma.z + ch];
    uint32_t d3 = gF[ma.w + ch];
    float4 wza = *(const float4*)&wz[mi];
    float4 wha = *(const float4*)&wh[mi];
    MACLO(az, wza.x, d0); MACHI(ah, wha.x, d0);
    MACLO(az, wza.y, d1); MACHI(ah, wha.y, d1);
    MACLO(az, wza.z, d2); MACHI(ah, wha.z, d2);
    MACLO(az, wza.w, d3); MACHI(ah, wha.w, d3);
  }
  az *= rsz;
  ah *= rsh;

  // ---- epilogue: ELU + bias + self -> fp16-packed pre-gate dword ----
  f16x2 sp = __builtin_bit_cast(f16x2, spd);
  float vz = az + bgz[ch]; vz = vz > 0.f ? vz : __expf(vz) - 1.f;
  float vh = ah + bgh[ch]; vh = vh > 0.f ? vh : __expf(vh) - 1.f;
  f16x2 pre = {(_Float16)(vz + (float)sp.x), (_Float16)(vh + (float)sp.y)};
  abuf[(size_t)(rb + nl) * 64 + ch] = __builtin_bit_cast(uint32_t, pre);
}

// ---------------------------------------------------------------------------
// GRU recurrence: one lane per (node, channel); 12-step serial chain on
// fp16-packed pre-gate values (25 MB coalesced read). BN fused at the end.
__global__ __launch_bounds__(256) void gru_k(
    const uint32_t* __restrict__ abuf,
    const float* __restrict__ gam, const float* __restrict__ bet,
    const float* __restrict__ mu, const float* __restrict__ var,
    float* __restrict__ out) {
  const int gtid = blockIdx.x * 256 + threadIdx.x;   // [0, NB*NN*64)
  const int node = gtid >> 6, ch = gtid & 63;
  const int b = node >> 11, nl = node & (NN - 1);
  float hc = 0.f;
#pragma unroll
  for (int t = 0; t < NT; t++) {
    f16x2 pre = __builtin_bit_cast(
        f16x2, abuf[(size_t)((b * NT + t) * NN + nl) * 64 + ch]);
    float zg = RCPF(1.f + __expf(-((float)pre.x + hc)));      // sigmoid
    float ta = (float)pre.y + hc;
    float tg = 1.f - 2.f * RCPF(__expf(2.f * ta) + 1.f);      // tanh
    hc = zg * hc + (1.f - zg) * tg;
  }
  out[gtid] = (hc - mu[ch]) * rsqrtf(var[ch] + 1e-3f) * gam[ch] + bet[ch];
}

// ---------------------------------------------------------------------------
extern "C" void kernel_launch(void* const* d_in, const int* in_sizes, int n_in,
                              void* d_out, int out_size, void* d_ws, size_t ws_size,
                              hipStream_t stream) {
  (void)in_sizes; (void)n_in; (void)out_size; (void)ws_size;
  const float* X   = (const float*)d_in[0];
  const float* bm  = (const float*)d_in[1];
  const float* Wz  = (const float*)d_in[2];
  const float* Zb  = (const float*)d_in[3];
  const float* Wh  = (const float*)d_in[4];
  const float* Hb  = (const float*)d_in[5];
  const float* Wgz = (const float*)d_in[6];
  const float* a1z = (const float*)d_in[7];
  const float* a2z = (const float*)d_in[8];
  const float* bgz = (const float*)d_in[9];
  const float* Wgh = (const float*)d_in[10];
  const float* a1h = (const float*)d_in[11];
  const float* a2h = (const float*)d_in[12];
  const float* bgh = (const float*)d_in[13];
  const float* gam = (const float*)d_in[14];
  const float* bet = (const float*)d_in[15];
  const float* mu  = (const float*)d_in[16];
  const float* var = (const float*)d_in[17];
  float* out = (float*)d_out;

  char* p = (char*)d_ws;
  uint32_t* gbufF = (uint32_t*)p; p += (size_t)NR * 64 * sizeof(uint32_t);  // 25 MB
  uint32_t* gbufS = (uint32_t*)p; p += (size_t)NR * 64 * sizeof(uint32_t);  // 25 MB
  float*    fbuf  = (float*)p;    p += (size_t)NR * 16 * sizeof(float);     // 6 MB
  uint32_t* abuf  = (uint32_t*)p; p += (size_t)NR * 64 * sizeof(uint32_t);  // 25 MB
  int*      adj   = (int*)p;      p += (size_t)NB * NN * MAXD * sizeof(int);// 2 MB
  int*      deg   = (int*)p;      p += (size_t)NB * NN * sizeof(int);       // 32 KB
  _Float16* W16   = (_Float16*)p; p += 272 * 64 * sizeof(_Float16);         // 34 KB
  float*    biasC = (float*)p;    p += 128 * sizeof(float);

  prep_w_k<<<dim3(68), dim3(256), 0, stream>>>(
      Wgz, Wgh, Wz, Wh, a1z, a2z, a1h, a2h, Zb, Hb, W16, biasC);
  build_adj_k<<<dim3(NB * NN / 4), dim3(256), 0, stream>>>(bm, adj, deg);
  mfma_gemm_k<<<dim3(NR / 64), dim3(256), 0, stream>>>(
      X, W16, biasC, gbufF, gbufS, fbuf);
  attn_k<<<dim3(NB * NN / 4, NT), dim3(256), 0, stream>>>(
      gbufF, gbufS, fbuf, adj, deg, bgz, bgh, abuf);
  gru_k<<<dim3(NB * NN * 64 / 256), dim3(256), 0, stream>>>(
      abuf, gam, bet, mu, var, out);
}

// Round 9
// 233.788 us; speedup vs baseline: 1.8691x; 1.0301x over previous
//
#include <hip/hip_runtime.h>
#include <cstdint>
#include <cstddef>

// Problem constants (fixed by setup_inputs)
#define NB 4      // batch
#define NT 12     // timesteps
#define NN 2048   // nodes
#define NF 64     // in features
#define NH 4      // heads
#define ND 16     // head dim
#define NC 64     // out channels
#define MAXD 64   // max neighbors kept (Binomial(2047,16/2048): P(deg>64)~1e-19)
#define NR (NB * NT * NN)  // 98304 batched GEMM rows

typedef _Float16 f16x8 __attribute__((ext_vector_type(8)));
typedef _Float16 f16x2 __attribute__((ext_vector_type(2)));
typedef float f32x4 __attribute__((ext_vector_type(4)));

// LeakyReLU 0.2: max(v, 0.2v) is exact for both signs (2 VALU: mul+max)
#define LR(v) fmaxf((v), 0.2f * (v))
#define RCPF(x) __builtin_amdgcn_rcpf(x)

// v_fma_mix_f32: acc += w * (f32)(f16 half of d).
#define MACLO(acc, w, d)                                                      \
  asm("v_fma_mix_f32 %0, %1, %2, %0 op_sel:[0,0,0] op_sel_hi:[0,1,0]"         \
      : "+v"(acc) : "v"(w), "v"(d))
#define MACHI(acc, w, d)                                                      \
  asm("v_fma_mix_f32 %0, %1, %2, %0 op_sel:[0,1,0] op_sel_hi:[0,1,0]"         \
      : "+v"(acc) : "v"(w), "v"(d))

// ---------------------------------------------------------------------------
// Build padded adjacency lists from the additive mask (one wave/row), with
// the weight-prep work fused in as extra trailing blocks (saves a launch).
__global__ __launch_bounds__(256) void build_adj_k(
    const float* __restrict__ bias, int* __restrict__ adj, int* __restrict__ deg,
    const float* __restrict__ Wgz, const float* __restrict__ Wgh,
    const float* __restrict__ Wz,  const float* __restrict__ Wh,
    const float* __restrict__ a1z, const float* __restrict__ a2z,
    const float* __restrict__ a1h, const float* __restrict__ a2h,
    const float* __restrict__ Zb,  const float* __restrict__ Hb,
    _Float16* __restrict__ W16, float* __restrict__ biasC) {
  if (blockIdx.x >= NB * NN / 4) {          // ---- fused prep_w blocks ----
    int idx = (blockIdx.x - NB * NN / 4) * 256 + threadIdx.x;
    if (idx < 272 * 64) {
      int c = idx >> 6, k = idx & 63;
      float w;
      if (c < 64)       w = Wgz[((c >> 4) << 10) + (k << 4) + (c & 15)];
      else if (c < 128) { int q = c - 64; w = Wgh[((q >> 4) << 10) + (k << 4) + (q & 15)]; }
      else if (c < 192) w = Wz[(k << 6) + (c - 128)];
      else if (c < 256) w = Wh[(k << 6) + (c - 192)];
      else {
        int j = c - 256, h = j & 3;
        const float* Wg = (j & 4) ? Wgh : Wgz;
        const float* av = (j & 8) ? ((j & 4) ? a2h : a2z) : ((j & 4) ? a1h : a1z);
        float s = 0.f;
#pragma unroll
        for (int d = 0; d < 16; d++)
          s = fmaf(Wg[(h << 10) + (k << 4) + d], av[(h << 4) + d], s);
        w = s;
      }
      W16[idx] = (_Float16)w;
    }
    if (blockIdx.x == NB * NN / 4 && threadIdx.x < 128)
      biasC[threadIdx.x] =
          (threadIdx.x < 64) ? Zb[threadIdx.x] : Hb[threadIdx.x - 64];
    return;
  }
  int gtid = blockIdx.x * 256 + threadIdx.x;
  int wid = gtid >> 6;            // row id in [0, NB*NN)
  int lane = threadIdx.x & 63;
  const float* row = bias + (size_t)wid * NN;
  int* arow = adj + (size_t)wid * MAXD;
  int count = 0;
  for (int c0 = 0; c0 < NN; c0 += 64) {
    float v = __builtin_nontemporal_load(row + c0 + lane);  // 67 MB single-use
    bool e = (v > -1e8f);                       // edge iff mask == 0
    unsigned long long m = __ballot(e);
    int pre = __popcll(m & ((1ull << lane) - 1ull));
    if (e) {
      int pos = count + pre;
      if (pos < MAXD) arow[pos] = c0 + lane;
    }
    count += __popcll(m);
  }
  if (lane == 0) deg[wid] = count < MAXD ? count : MAXD;
}

// ---------------------------------------------------------------------------
// fp16 MFMA GEMM: [98304 x 64] @ [64 x 272], fp32 accumulate. (unchanged)
__global__ __launch_bounds__(256) void mfma_gemm_k(
    const float* __restrict__ X, const _Float16* __restrict__ W16,
    const float* __restrict__ biasC,
    uint32_t* __restrict__ gbufF, uint32_t* __restrict__ gbufS,
    float* __restrict__ fbuf) {
  __shared__ uint32_t tr[4][16 * 68];   // per-wave 16 rows x 64 cols (+pad)
  const int tid = threadIdx.x;
  const int wv = tid >> 6, lane = tid & 63;
  const int m = lane & 15, quad = lane >> 4;
  const unsigned rw = blockIdx.x * 64 + wv * 16;      // wave's row base
  uint32_t* tw = tr[wv];

  const float* xr = X + (size_t)(rw + m) * 64;
  float4 x0 = *(const float4*)(xr + quad * 8);
  float4 x1 = *(const float4*)(xr + quad * 8 + 4);
  float4 x2 = *(const float4*)(xr + 32 + quad * 8);
  float4 x3 = *(const float4*)(xr + 32 + quad * 8 + 4);
  f16x8 A0 = {(_Float16)x0.x, (_Float16)x0.y, (_Float16)x0.z, (_Float16)x0.w,
              (_Float16)x1.x, (_Float16)x1.y, (_Float16)x1.z, (_Float16)x1.w};
  f16x8 A1 = {(_Float16)x2.x, (_Float16)x2.y, (_Float16)x2.z, (_Float16)x2.w,
              (_Float16)x3.x, (_Float16)x3.y, (_Float16)x3.z, (_Float16)x3.w};

  float bzc[4], bhc[4];
#pragma unroll
  for (int j = 0; j < 4; j++) {
    bzc[j] = biasC[j * 16 + m];
    bhc[j] = biasC[64 + j * 16 + m];
  }
  const int rsub = lane >> 4, chk = lane & 15;   // readback: row-sub, chunk

  f32x4 zacc[4], zs[4];
#pragma unroll
  for (int ct = 0; ct < 17; ct++) {
    const _Float16* wp = W16 + (ct * 16 + m) * 64;
    f16x8 B0 = *(const f16x8*)(wp + quad * 8);
    f16x8 B1 = *(const f16x8*)(wp + 32 + quad * 8);
    f32x4 acc = {0.f, 0.f, 0.f, 0.f};
    acc = __builtin_amdgcn_mfma_f32_16x16x32_f16(A0, B0, acc, 0, 0, 0);
    acc = __builtin_amdgcn_mfma_f32_16x16x32_f16(A1, B1, acc, 0, 0, 0);
    // C-layout: row = quad*4 + r, col = ct*16 + m  [measured: learn_hip m89]
    if (ct < 4) {
      zacc[ct] = acc;                        // z-feat tiles, saved for pairing
    } else if (ct < 8) {
      const int j = ct - 4;                  // h-feat tile -> pack {z,h}
#pragma unroll
      for (int r = 0; r < 4; r++) {
        f16x2 pv = {(_Float16)zacc[j][r], (_Float16)acc[r]};
        tw[(quad * 4 + r) * 68 + j * 16 + m] = __builtin_bit_cast(uint32_t, pv);
      }
      if (ct == 7) {   // full-tile readback: 4 stores x (16 lanes = 256B row)
#pragma unroll
        for (int i = 0; i < 4; i++) {
          int row = i * 4 + rsub;
          uint4 v = *(const uint4*)&tw[row * 68 + chk * 4];
          *(uint4*)&gbufF[(size_t)(rw + row) * 64 + chk * 4] = v;
        }
      }
    } else if (ct < 12) {
#pragma unroll
      for (int r = 0; r < 4; r++) zs[ct - 8][r] = acc[r] + bzc[ct - 8];
    } else if (ct < 16) {
      const int j = ct - 12;
#pragma unroll
      for (int r = 0; r < 4; r++) {
        f16x2 pv = {(_Float16)zs[j][r], (_Float16)(acc[r] + bhc[j])};
        tw[(quad * 4 + r) * 68 + j * 16 + m] = __builtin_bit_cast(uint32_t, pv);
      }
      if (ct == 15) {
#pragma unroll
        for (int i = 0; i < 4; i++) {
          int row = i * 4 + rsub;
          uint4 v = *(const uint4*)&tw[row * 68 + chk * 4];
          *(uint4*)&gbufS[(size_t)(rw + row) * 64 + chk * 4] = v;
        }
      }
    } else {
      const unsigned rb = rw + quad * 4;
#pragma unroll
      for (int r = 0; r < 4; r++) fbuf[(size_t)(rb + r) * 16 + m] = acc[r];
    }
  }
}

// ---------------------------------------------------------------------------
// Attention, R9 = R8 + batch->XCD affinity + 1-VALU gather addressing.
//  - XCD batch affinity: R8's FETCH (125 MB vs 58 MB unique) = every XCD
//    re-fetching every (b,t) slab (gather is random across the full batch,
//    so slab duplication count = #XCDs touching that batch). Remap
//    b = (bid&7)>>1: XCD pair {2b,2b+1} serves batch b only -> per-XCD
//    working slab 512KB gF + 128KB fbuf = L2-resident, duplication 8x -> 2x.
//  - adjS holds BYTE row offsets (<<8); per-lane ch4 hoisted: gather byte
//    offset = 1 v_add (SGPR-base + voffset load). Phase 1 recovers the fbuf
//    offset with one >>2 (fbuf row = 64B = gbuf row/4).
//  - Keeps all R8 cuts: cooperative row-sum, fma_mix MACs, 4-granular pad,
//    fmaxf-LR, early self pre-gate load.
__global__ __launch_bounds__(256) void attn_k(
    const uint32_t* __restrict__ gbufF, const uint32_t* __restrict__ gbufS,
    const float* __restrict__ fbuf,
    const int* __restrict__ adj, const int* __restrict__ deg,
    const float* __restrict__ bgz, const float* __restrict__ bgh,
    uint32_t* __restrict__ abuf) {
  __shared__ int adjS[4][MAXD];         // pre-shifted neighbor BYTE offsets (<<8)
  __shared__ float wexp[4][8][68];      // stride 68 kills head-alias
  const int tid = threadIdx.x;
  const int lane = tid & 63;
  const int ws = tid >> 6;
  // batch->XCD affinity remap (bijective over grid.x = 2048):
  const int bid = blockIdx.x;
  const int g = bid & 7;                // XCD slot
  const int b = g >> 1;                 // batch owned by XCD pair
  const int grp = (bid >> 3) * 2 + (g & 1);   // node-group within batch 0..511
  const int nl = grp * 4 + ws;
  const int node = b * NN + nl;
  const int t = blockIdx.y;
  const int dg = deg[node];
  adjS[ws][lane] = (lane < dg) ? (adj[node * MAXD + lane] << 8) : 0;
  const int dgp = (dg + 3) & ~3;        // 4-granular pad
  const int ch = lane, hh = lane >> 4;
  const uint32_t ch4 = (uint32_t)ch << 2;
  const int sr = lane & 7, ss = lane >> 3;   // sum-reduce: row, segment

  const unsigned rb = (unsigned)(b * NT + t) * NN;
  const float* fb = fbuf + (size_t)rb * 16;
  const char* gFc = (const char*)(gbufF + (size_t)rb * 64);
  // self pre-gate dword: issue now, consumed in epilogue
  const uint32_t spd = gbufS[((size_t)rb + nl) * 64 + ch];

  // ---- phase 1: raw exp attention weights (lane = neighbor slot) ----
  {
    const float4* p = (const float4*)(fb + nl * 16);
    float4 f1z = p[0], f1h = p[1];
    if (lane < dg) {                    // exec-masked: inactive lanes load 0 B
      const float4* q = (const float4*)((const char*)fb +
                                        ((unsigned)adjS[ws][lane] >> 2));
      float4 f2z = q[2], f2h = q[3];
      wexp[ws][0][lane] = __expf(LR(f1z.x + f2z.x));
      wexp[ws][1][lane] = __expf(LR(f1z.y + f2z.y));
      wexp[ws][2][lane] = __expf(LR(f1z.z + f2z.z));
      wexp[ws][3][lane] = __expf(LR(f1z.w + f2z.w));
      wexp[ws][4][lane] = __expf(LR(f1h.x + f2h.x));
      wexp[ws][5][lane] = __expf(LR(f1h.y + f2h.y));
      wexp[ws][6][lane] = __expf(LR(f1h.z + f2h.z));
      wexp[ws][7][lane] = __expf(LR(f1h.w + f2h.w));
    } else {
#pragma unroll
      for (int k = 0; k < 8; k++) wexp[ws][k][lane] = 0.f;
    }
  }

  // ---- phase 1.5: cooperative row sums (same-wave LDS ordering) ----
  float4 u0 = *(const float4*)&wexp[ws][sr][ss * 8];
  float4 u1 = *(const float4*)&wexp[ws][sr][ss * 8 + 4];
  float part = ((u0.x + u0.y) + (u0.z + u0.w)) +
               ((u1.x + u1.y) + (u1.z + u1.w));
  part += __shfl_xor(part, 8);
  part += __shfl_xor(part, 16);
  part += __shfl_xor(part, 32);
  const float rsz = RCPF(__shfl(part, hh));       // row hh lives in lane hh
  const float rsh = RCPF(__shfl(part, 4 + hh));

  // ---- phase 2: 8-wide gather (8 loads in flight) + 4-wide remainder ----
  float az = 0.f, ah = 0.f;
  const float* wz = wexp[ws][hh];
  const float* wh = wexp[ws][4 + hh];
  int mi = 0;
  for (; mi + 8 <= dgp; mi += 8) {
    int4 ma = *(const int4*)&adjS[ws][mi];
    int4 mb = *(const int4*)&adjS[ws][mi + 4];
    uint32_t d0 = *(const uint32_t*)(gFc + ((uint32_t)ma.x + ch4));
    uint32_t d1 = *(const uint32_t*)(gFc + ((uint32_t)ma.y + ch4));
    uint32_t d2 = *(const uint32_t*)(gFc + ((uint32_t)ma.z + ch4));
    uint32_t d3 = *(const uint32_t*)(gFc + ((uint32_t)ma.w + ch4));
    uint32_t d4 = *(const uint32_t*)(gFc + ((uint32_t)mb.x + ch4));
    uint32_t d5 = *(const uint32_t*)(gFc + ((uint32_t)mb.y + ch4));
    uint32_t d6 = *(const uint32_t*)(gFc + ((uint32_t)mb.z + ch4));
    uint32_t d7 = *(const uint32_t*)(gFc + ((uint32_t)mb.w + ch4));
    float4 wza = *(const float4*)&wz[mi];
    float4 wzb = *(const float4*)&wz[mi + 4];
    float4 wha = *(const float4*)&wh[mi];
    float4 whb = *(const float4*)&wh[mi + 4];
    MACLO(az, wza.x, d0); MACHI(ah, wha.x, d0);
    MACLO(az, wza.y, d1); MACHI(ah, wha.y, d1);
    MACLO(az, wza.z, d2); MACHI(ah, wha.z, d2);
    MACLO(az, wza.w, d3); MACHI(ah, wha.w, d3);
    MACLO(az, wzb.x, d4); MACHI(ah, whb.x, d4);
    MACLO(az, wzb.y, d5); MACHI(ah, whb.y, d5);
    MACLO(az, wzb.z, d6); MACHI(ah, whb.z, d6);
    MACLO(az, wzb.w, d7); MACHI(ah, whb.w, d7);
  }
  if (mi < dgp) {                      // dgp is 4-granular: exactly 4 left
    int4 ma = *(const int4*)&adjS[ws][mi];
    uint32_t d0 = *(const uint32_t*)(gFc + ((uint32_t)ma.x + ch4));
    uint32_t d1 = *(const uint32_t*)(gFc + ((uint32_t)ma.y + ch4));
    uint32_t d2 = *(const uint32_t*)(gFc + ((uint32_t)ma.z + ch4));
    uint32_t d3 = *(const uint32_t*)(gFc + ((uint32_t)ma.w + ch4));
    float4 wza = *(const float4*)&wz[mi];
    float4 wha = *(const float4*)&wh[mi];
    MACLO(az, wza.x, d0); MACHI(ah, wha.x, d0);
    MACLO(az, wza.y, d1); MACHI(ah, wha.y, d1);
    MACLO(az, wza.z, d2); MACHI(ah, wha.z, d2);
    MACLO(az, wza.w, d3); MACHI(ah, wha.w, d3);
  }
  az *= rsz;
  ah *= rsh;

  // ---- epilogue: ELU + bias + self -> fp16-packed pre-gate dword ----
  f16x2 sp = __builtin_bit_cast(f16x2, spd);
  float vz = az + bgz[ch]; vz = vz > 0.f ? vz : __expf(vz) - 1.f;
  float vh = ah + bgh[ch]; vh = vh > 0.f ? vh : __expf(vh) - 1.f;
  f16x2 pre = {(_Float16)(vz + (float)sp.x), (_Float16)(vh + (float)sp.y)};
  abuf[(size_t)(rb + nl) * 64 + ch] = __builtin_bit_cast(uint32_t, pre);
}

// ---------------------------------------------------------------------------
// GRU recurrence: one lane per (node, channel); 12-step serial chain on
// fp16-packed pre-gate values (25 MB coalesced read). BN fused at the end.
__global__ __launch_bounds__(256) void gru_k(
    const uint32_t* __restrict__ abuf,
    const float* __restrict__ gam, const float* __restrict__ bet,
    const float* __restrict__ mu, const float* __restrict__ var,
    float* __restrict__ out) {
  const int gtid = blockIdx.x * 256 + threadIdx.x;   // [0, NB*NN*64)
  const int node = gtid >> 6, ch = gtid & 63;
  const int b = node >> 11, nl = node & (NN - 1);
  float hc = 0.f;
#pragma unroll
  for (int t = 0; t < NT; t++) {
    f16x2 pre = __builtin_bit_cast(
        f16x2, abuf[(size_t)((b * NT + t) * NN + nl) * 64 + ch]);
    float zg = RCPF(1.f + __expf(-((float)pre.x + hc)));      // sigmoid
    float ta = (float)pre.y + hc;
    float tg = 1.f - 2.f * RCPF(__expf(2.f * ta) + 1.f);      // tanh
    hc = zg * hc + (1.f - zg) * tg;
  }
  out[gtid] = (hc - mu[ch]) * rsqrtf(var[ch] + 1e-3f) * gam[ch] + bet[ch];
}

// ---------------------------------------------------------------------------
extern "C" void kernel_launch(void* const* d_in, const int* in_sizes, int n_in,
                              void* d_out, int out_size, void* d_ws, size_t ws_size,
                              hipStream_t stream) {
  (void)in_sizes; (void)n_in; (void)out_size; (void)ws_size;
  const float* X   = (const float*)d_in[0];
  const float* bm  = (const float*)d_in[1];
  const float* Wz  = (const float*)d_in[2];
  const float* Zb  = (const float*)d_in[3];
  const float* Wh  = (const float*)d_in[4];
  const float* Hb  = (const float*)d_in[5];
  const float* Wgz = (const float*)d_in[6];
  const float* a1z = (const float*)d_in[7];
  const float* a2z = (const float*)d_in[8];
  const float* bgz = (const float*)d_in[9];
  const float* Wgh = (const float*)d_in[10];
  const float* a1h = (const float*)d_in[11];
  const float* a2h = (const float*)d_in[12];
  const float* bgh = (const float*)d_in[13];
  const float* gam = (const float*)d_in[14];
  const float* bet = (const float*)d_in[15];
  const float* mu  = (const float*)d_in[16];
  const float* var = (const float*)d_in[17];
  float* out = (float*)d_out;

  char* p = (char*)d_ws;
  uint32_t* gbufF = (uint32_t*)p; p += (size_t)NR * 64 * sizeof(uint32_t);  // 25 MB
  uint32_t* gbufS = (uint32_t*)p; p += (size_t)NR * 64 * sizeof(uint32_t);  // 25 MB
  float*    fbuf  = (float*)p;    p += (size_t)NR * 16 * sizeof(float);     // 6 MB
  uint32_t* abuf  = (uint32_t*)p; p += (size_t)NR * 64 * sizeof(uint32_t);  // 25 MB
  int*      adj   = (int*)p;      p += (size_t)NB * NN * MAXD * sizeof(int);// 2 MB
  int*      deg   = (int*)p;      p += (size_t)NB * NN * sizeof(int);       // 32 KB
  _Float16* W16   = (_Float16*)p; p += 272 * 64 * sizeof(_Float16);         // 34 KB
  float*    biasC = (float*)p;    p += 128 * sizeof(float);

  build_adj_k<<<dim3(NB * NN / 4 + 68), dim3(256), 0, stream>>>(
      bm, adj, deg, Wgz, Wgh, Wz, Wh, a1z, a2z, a1h, a2h, Zb, Hb, W16, biasC);
  mfma_gemm_k<<<dim3(NR / 64), dim3(256), 0, stream>>>(
      X, W16, biasC, gbufF, gbufS, fbuf);
  attn_k<<<dim3(NB * NN / 4, NT), dim3(256), 0, stream>>>(
      gbufF, gbufS, fbuf, adj, deg, bgz, bgh, abuf);
  gru_k<<<dim3(NB * NN * 64 / 256), dim3(256), 0, stream>>>(
      abuf, gam, bet, mu, var, out);
}

// Round 10
// 232.778 us; speedup vs baseline: 1.8772x; 1.0043x over previous
//
#include <hip/hip_runtime.h>
#include <cstdint>
#include <cstddef>

// Problem constants (fixed by setup_inputs)
#define NB 4      // batch
#define NT 12     // timesteps
#define NN 2048   // nodes
#define NF 64     // in features
#define NH 4      // heads
#define ND 16     // head dim
#define NC 64     // out channels
#define MAXD 64   // max neighbors kept (Binomial(2047,16/2048): P(deg>64)~1e-19)
#define NR (NB * NT * NN)  // 98304 batched GEMM rows

typedef _Float16 f16x8 __attribute__((ext_vector_type(8)));
typedef _Float16 f16x2 __attribute__((ext_vector_type(2)));
typedef float f32x4 __attribute__((ext_vector_type(4)));

// LeakyReLU 0.2: max(v, 0.2v) is exact for both signs (2 VALU: mul+max)
#define LR(v) fmaxf((v), 0.2f * (v))
#define RCPF(x) __builtin_amdgcn_rcpf(x)

// v_fma_mix_f32: acc += w * (f32)(f16 half of d).
#define MACLO(acc, w, d)                                                      \
  asm("v_fma_mix_f32 %0, %1, %2, %0 op_sel:[0,0,0] op_sel_hi:[0,1,0]"         \
      : "+v"(acc) : "v"(w), "v"(d))
#define MACHI(acc, w, d)                                                      \
  asm("v_fma_mix_f32 %0, %1, %2, %0 op_sel:[0,1,0] op_sel_hi:[0,1,0]"         \
      : "+v"(acc) : "v"(w), "v"(d))

// ---------------------------------------------------------------------------
// Build padded adjacency lists from the additive mask (one wave/row), with
// the weight-prep work fused in as extra trailing blocks (saves a launch).
__global__ __launch_bounds__(256) void build_adj_k(
    const float* __restrict__ bias, int* __restrict__ adj, int* __restrict__ deg,
    const float* __restrict__ Wgz, const float* __restrict__ Wgh,
    const float* __restrict__ Wz,  const float* __restrict__ Wh,
    const float* __restrict__ a1z, const float* __restrict__ a2z,
    const float* __restrict__ a1h, const float* __restrict__ a2h,
    const float* __restrict__ Zb,  const float* __restrict__ Hb,
    _Float16* __restrict__ W16, float* __restrict__ biasC) {
  if (blockIdx.x >= NB * NN / 4) {          // ---- fused prep_w blocks ----
    int idx = (blockIdx.x - NB * NN / 4) * 256 + threadIdx.x;
    if (idx < 272 * 64) {
      int c = idx >> 6, k = idx & 63;
      float w;
      if (c < 64)       w = Wgz[((c >> 4) << 10) + (k << 4) + (c & 15)];
      else if (c < 128) { int q = c - 64; w = Wgh[((q >> 4) << 10) + (k << 4) + (q & 15)]; }
      else if (c < 192) w = Wz[(k << 6) + (c - 128)];
      else if (c < 256) w = Wh[(k << 6) + (c - 192)];
      else {
        int j = c - 256, h = j & 3;
        const float* Wg = (j & 4) ? Wgh : Wgz;
        const float* av = (j & 8) ? ((j & 4) ? a2h : a2z) : ((j & 4) ? a1h : a1z);
        float s = 0.f;
#pragma unroll
        for (int d = 0; d < 16; d++)
          s = fmaf(Wg[(h << 10) + (k << 4) + d], av[(h << 4) + d], s);
        w = s;
      }
      W16[idx] = (_Float16)w;
    }
    if (blockIdx.x == NB * NN / 4 && threadIdx.x < 128)
      biasC[threadIdx.x] =
          (threadIdx.x < 64) ? Zb[threadIdx.x] : Hb[threadIdx.x - 64];
    return;
  }
  int gtid = blockIdx.x * 256 + threadIdx.x;
  int wid = gtid >> 6;            // row id in [0, NB*NN)
  int lane = threadIdx.x & 63;
  const float* row = bias + (size_t)wid * NN;
  int* arow = adj + (size_t)wid * MAXD;
  int count = 0;
  for (int c0 = 0; c0 < NN; c0 += 64) {
    float v = __builtin_nontemporal_load(row + c0 + lane);  // 67 MB single-use
    bool e = (v > -1e8f);                       // edge iff mask == 0
    unsigned long long m = __ballot(e);
    int pre = __popcll(m & ((1ull << lane) - 1ull));
    if (e) {
      int pos = count + pre;
      if (pos < MAXD) arow[pos] = c0 + lane;
    }
    count += __popcll(m);
  }
  if (lane == 0) deg[wid] = count < MAXD ? count : MAXD;
}

// ---------------------------------------------------------------------------
// fp16 MFMA GEMM: [98304 x 64] @ [64 x 272], fp32 accumulate. (unchanged)
__global__ __launch_bounds__(256) void mfma_gemm_k(
    const float* __restrict__ X, const _Float16* __restrict__ W16,
    const float* __restrict__ biasC,
    uint32_t* __restrict__ gbufF, uint32_t* __restrict__ gbufS,
    float* __restrict__ fbuf) {
  __shared__ uint32_t tr[4][16 * 68];   // per-wave 16 rows x 64 cols (+pad)
  const int tid = threadIdx.x;
  const int wv = tid >> 6, lane = tid & 63;
  const int m = lane & 15, quad = lane >> 4;
  const unsigned rw = blockIdx.x * 64 + wv * 16;      // wave's row base
  uint32_t* tw = tr[wv];

  const float* xr = X + (size_t)(rw + m) * 64;
  float4 x0 = *(const float4*)(xr + quad * 8);
  float4 x1 = *(const float4*)(xr + quad * 8 + 4);
  float4 x2 = *(const float4*)(xr + 32 + quad * 8);
  float4 x3 = *(const float4*)(xr + 32 + quad * 8 + 4);
  f16x8 A0 = {(_Float16)x0.x, (_Float16)x0.y, (_Float16)x0.z, (_Float16)x0.w,
              (_Float16)x1.x, (_Float16)x1.y, (_Float16)x1.z, (_Float16)x1.w};
  f16x8 A1 = {(_Float16)x2.x, (_Float16)x2.y, (_Float16)x2.z, (_Float16)x2.w,
              (_Float16)x3.x, (_Float16)x3.y, (_Float16)x3.z, (_Float16)x3.w};

  float bzc[4], bhc[4];
#pragma unroll
  for (int j = 0; j < 4; j++) {
    bzc[j] = biasC[j * 16 + m];
    bhc[j] = biasC[64 + j * 16 + m];
  }
  const int rsub = lane >> 4, chk = lane & 15;   // readback: row-sub, chunk

  f32x4 zacc[4], zs[4];
#pragma unroll
  for (int ct = 0; ct < 17; ct++) {
    const _Float16* wp = W16 + (ct * 16 + m) * 64;
    f16x8 B0 = *(const f16x8*)(wp + quad * 8);
    f16x8 B1 = *(const f16x8*)(wp + 32 + quad * 8);
    f32x4 acc = {0.f, 0.f, 0.f, 0.f};
    acc = __builtin_amdgcn_mfma_f32_16x16x32_f16(A0, B0, acc, 0, 0, 0);
    acc = __builtin_amdgcn_mfma_f32_16x16x32_f16(A1, B1, acc, 0, 0, 0);
    // C-layout: row = quad*4 + r, col = ct*16 + m  [measured: learn_hip m89]
    if (ct < 4) {
      zacc[ct] = acc;                        // z-feat tiles, saved for pairing
    } else if (ct < 8) {
      const int j = ct - 4;                  // h-feat tile -> pack {z,h}
#pragma unroll
      for (int r = 0; r < 4; r++) {
        f16x2 pv = {(_Float16)zacc[j][r], (_Float16)acc[r]};
        tw[(quad * 4 + r) * 68 + j * 16 + m] = __builtin_bit_cast(uint32_t, pv);
      }
      if (ct == 7) {   // full-tile readback: 4 stores x (16 lanes = 256B row)
#pragma unroll
        for (int i = 0; i < 4; i++) {
          int row = i * 4 + rsub;
          uint4 v = *(const uint4*)&tw[row * 68 + chk * 4];
          *(uint4*)&gbufF[(size_t)(rw + row) * 64 + chk * 4] = v;
        }
      }
    } else if (ct < 12) {
#pragma unroll
      for (int r = 0; r < 4; r++) zs[ct - 8][r] = acc[r] + bzc[ct - 8];
    } else if (ct < 16) {
      const int j = ct - 12;
#pragma unroll
      for (int r = 0; r < 4; r++) {
        f16x2 pv = {(_Float16)zs[j][r], (_Float16)(acc[r] + bhc[j])};
        tw[(quad * 4 + r) * 68 + j * 16 + m] = __builtin_bit_cast(uint32_t, pv);
      }
      if (ct == 15) {
#pragma unroll
        for (int i = 0; i < 4; i++) {
          int row = i * 4 + rsub;
          uint4 v = *(const uint4*)&tw[row * 68 + chk * 4];
          *(uint4*)&gbufS[(size_t)(rw + row) * 64 + chk * 4] = v;
        }
      }
    } else {
      const unsigned rb = rw + quad * 4;
#pragma unroll
      for (int r = 0; r < 4; r++) fbuf[(size_t)(rb + r) * 16 + m] = acc[r];
    }
  }
}

// ---------------------------------------------------------------------------
// Attention, R10 = R9 + 16-deep gather MLP.
//  Measured R9: VALUBusy 66%. Phase-2 analysis: 8 loads then 16 fma_mix
//  (~32cy VALU burst); 8 waves/SIMD x 32cy = 256cy coverage < ~400cy L2
//  latency -> 64% busy ceiling (matches). Widening to 16 loads + 32 MACs
//  per batch doubles the burst (8 x 64 = 512cy > latency) -> VALU-limited.
//  MAC order m0..m15 sequential = identical accumulation order (bit-exact).
//  Weight reads staged 8-at-a-time between MAC halves to keep VGPR <= 64
//  (__launch_bounds__(256,8) pins allocator; 8 blocks/CU preserved).
__global__ __launch_bounds__(256, 8) void attn_k(
    const uint32_t* __restrict__ gbufF, const uint32_t* __restrict__ gbufS,
    const float* __restrict__ fbuf,
    const int* __restrict__ adj, const int* __restrict__ deg,
    const float* __restrict__ bgz, const float* __restrict__ bgh,
    uint32_t* __restrict__ abuf) {
  __shared__ int adjS[4][MAXD];         // pre-shifted neighbor BYTE offsets (<<8)
  __shared__ float wexp[4][8][68];      // stride 68 kills head-alias
  const int tid = threadIdx.x;
  const int lane = tid & 63;
  const int ws = tid >> 6;
  // batch->XCD affinity remap (bijective over grid.x = 2048):
  const int bid = blockIdx.x;
  const int g = bid & 7;                // XCD slot
  const int b = g >> 1;                 // batch owned by XCD pair
  const int grp = (bid >> 3) * 2 + (g & 1);   // node-group within batch 0..511
  const int nl = grp * 4 + ws;
  const int node = b * NN + nl;
  const int t = blockIdx.y;
  const int dg = deg[node];
  adjS[ws][lane] = (lane < dg) ? (adj[node * MAXD + lane] << 8) : 0;
  const int dgp = (dg + 3) & ~3;        // 4-granular pad
  const int ch = lane, hh = lane >> 4;
  const uint32_t ch4 = (uint32_t)ch << 2;
  const int sr = lane & 7, ss = lane >> 3;   // sum-reduce: row, segment

  const unsigned rb = (unsigned)(b * NT + t) * NN;
  const float* fb = fbuf + (size_t)rb * 16;
  const char* gFc = (const char*)(gbufF + (size_t)rb * 64);
  // self pre-gate dword: issue now, consumed in epilogue
  const uint32_t spd = gbufS[((size_t)rb + nl) * 64 + ch];

  // ---- phase 1: raw exp attention weights (lane = neighbor slot) ----
  {
    const float4* p = (const float4*)(fb + nl * 16);
    float4 f1z = p[0], f1h = p[1];
    if (lane < dg) {                    // exec-masked: inactive lanes load 0 B
      const float4* q = (const float4*)((const char*)fb +
                                        ((unsigned)adjS[ws][lane] >> 2));
      float4 f2z = q[2], f2h = q[3];
      wexp[ws][0][lane] = __expf(LR(f1z.x + f2z.x));
      wexp[ws][1][lane] = __expf(LR(f1z.y + f2z.y));
      wexp[ws][2][lane] = __expf(LR(f1z.z + f2z.z));
      wexp[ws][3][lane] = __expf(LR(f1z.w + f2z.w));
      wexp[ws][4][lane] = __expf(LR(f1h.x + f2h.x));
      wexp[ws][5][lane] = __expf(LR(f1h.y + f2h.y));
      wexp[ws][6][lane] = __expf(LR(f1h.z + f2h.z));
      wexp[ws][7][lane] = __expf(LR(f1h.w + f2h.w));
    } else {
#pragma unroll
      for (int k = 0; k < 8; k++) wexp[ws][k][lane] = 0.f;
    }
  }

  // ---- phase 1.5: cooperative row sums (same-wave LDS ordering) ----
  float4 u0 = *(const float4*)&wexp[ws][sr][ss * 8];
  float4 u1 = *(const float4*)&wexp[ws][sr][ss * 8 + 4];
  float part = ((u0.x + u0.y) + (u0.z + u0.w)) +
               ((u1.x + u1.y) + (u1.z + u1.w));
  part += __shfl_xor(part, 8);
  part += __shfl_xor(part, 16);
  part += __shfl_xor(part, 32);
  const float rsz = RCPF(__shfl(part, hh));       // row hh lives in lane hh
  const float rsh = RCPF(__shfl(part, 4 + hh));

  // ---- phase 2: 16-deep gather, then 8-/4-wide remainders ----
  float az = 0.f, ah = 0.f;
  const float* wz = wexp[ws][hh];
  const float* wh = wexp[ws][4 + hh];
  int mi = 0;
  for (; mi + 16 <= dgp; mi += 16) {
    int4 ma = *(const int4*)&adjS[ws][mi];
    int4 mb = *(const int4*)&adjS[ws][mi + 4];
    int4 mc = *(const int4*)&adjS[ws][mi + 8];
    int4 md = *(const int4*)&adjS[ws][mi + 12];
    uint32_t d0 = *(const uint32_t*)(gFc + ((uint32_t)ma.x + ch4));
    uint32_t d1 = *(const uint32_t*)(gFc + ((uint32_t)ma.y + ch4));
    uint32_t d2 = *(const uint32_t*)(gFc + ((uint32_t)ma.z + ch4));
    uint32_t d3 = *(const uint32_t*)(gFc + ((uint32_t)ma.w + ch4));
    uint32_t d4 = *(const uint32_t*)(gFc + ((uint32_t)mb.x + ch4));
    uint32_t d5 = *(const uint32_t*)(gFc + ((uint32_t)mb.y + ch4));
    uint32_t d6 = *(const uint32_t*)(gFc + ((uint32_t)mb.z + ch4));
    uint32_t d7 = *(const uint32_t*)(gFc + ((uint32_t)mb.w + ch4));
    uint32_t d8 = *(const uint32_t*)(gFc + ((uint32_t)mc.x + ch4));
    uint32_t d9 = *(const uint32_t*)(gFc + ((uint32_t)mc.y + ch4));
    uint32_t dA = *(const uint32_t*)(gFc + ((uint32_t)mc.z + ch4));
    uint32_t dB = *(const uint32_t*)(gFc + ((uint32_t)mc.w + ch4));
    uint32_t dC = *(const uint32_t*)(gFc + ((uint32_t)md.x + ch4));
    uint32_t dD = *(const uint32_t*)(gFc + ((uint32_t)md.y + ch4));
    uint32_t dE = *(const uint32_t*)(gFc + ((uint32_t)md.z + ch4));
    uint32_t dF = *(const uint32_t*)(gFc + ((uint32_t)md.w + ch4));
    {
      float4 wza = *(const float4*)&wz[mi];
      float4 wzb = *(const float4*)&wz[mi + 4];
      float4 wha = *(const float4*)&wh[mi];
      float4 whb = *(const float4*)&wh[mi + 4];
      MACLO(az, wza.x, d0); MACHI(ah, wha.x, d0);
      MACLO(az, wza.y, d1); MACHI(ah, wha.y, d1);
      MACLO(az, wza.z, d2); MACHI(ah, wha.z, d2);
      MACLO(az, wza.w, d3); MACHI(ah, wha.w, d3);
      MACLO(az, wzb.x, d4); MACHI(ah, whb.x, d4);
      MACLO(az, wzb.y, d5); MACHI(ah, whb.y, d5);
      MACLO(az, wzb.z, d6); MACHI(ah, whb.z, d6);
      MACLO(az, wzb.w, d7); MACHI(ah, whb.w, d7);
    }
    {
      float4 wzc = *(const float4*)&wz[mi + 8];
      float4 wzd = *(const float4*)&wz[mi + 12];
      float4 whc = *(const float4*)&wh[mi + 8];
      float4 whd = *(const float4*)&wh[mi + 12];
      MACLO(az, wzc.x, d8); MACHI(ah, whc.x, d8);
      MACLO(az, wzc.y, d9); MACHI(ah, whc.y, d9);
      MACLO(az, wzc.z, dA); MACHI(ah, whc.z, dA);
      MACLO(az, wzc.w, dB); MACHI(ah, whc.w, dB);
      MACLO(az, wzd.x, dC); MACHI(ah, whd.x, dC);
      MACLO(az, wzd.y, dD); MACHI(ah, whd.y, dD);
      MACLO(az, wzd.z, dE); MACHI(ah, whd.z, dE);
      MACLO(az, wzd.w, dF); MACHI(ah, whd.w, dF);
    }
  }
  if (mi + 8 <= dgp) {
    int4 ma = *(const int4*)&adjS[ws][mi];
    int4 mb = *(const int4*)&adjS[ws][mi + 4];
    uint32_t d0 = *(const uint32_t*)(gFc + ((uint32_t)ma.x + ch4));
    uint32_t d1 = *(const uint32_t*)(gFc + ((uint32_t)ma.y + ch4));
    uint32_t d2 = *(const uint32_t*)(gFc + ((uint32_t)ma.z + ch4));
    uint32_t d3 = *(const uint32_t*)(gFc + ((uint32_t)ma.w + ch4));
    uint32_t d4 = *(const uint32_t*)(gFc + ((uint32_t)mb.x + ch4));
    uint32_t d5 = *(const uint32_t*)(gFc + ((uint32_t)mb.y + ch4));
    uint32_t d6 = *(const uint32_t*)(gFc + ((uint32_t)mb.z + ch4));
    uint32_t d7 = *(const uint32_t*)(gFc + ((uint32_t)mb.w + ch4));
    float4 wza = *(const float4*)&wz[mi];
    float4 wzb = *(const float4*)&wz[mi + 4];
    float4 wha = *(const float4*)&wh[mi];
    float4 whb = *(const float4*)&wh[mi + 4];
    MACLO(az, wza.x, d0); MACHI(ah, wha.x, d0);
    MACLO(az, wza.y, d1); MACHI(ah, wha.y, d1);
    MACLO(az, wza.z, d2); MACHI(ah, wha.z, d2);
    MACLO(az, wza.w, d3); MACHI(ah, wha.w, d3);
    MACLO(az, wzb.x, d4); MACHI(ah, whb.x, d4);
    MACLO(az, wzb.y, d5); MACHI(ah, whb.y, d5);
    MACLO(az, wzb.z, d6); MACHI(ah, whb.z, d6);
    MACLO(az, wzb.w, d7); MACHI(ah, whb.w, d7);
    mi += 8;
  }
  if (mi < dgp) {                      // dgp is 4-granular: exactly 4 left
    int4 ma = *(const int4*)&adjS[ws][mi];
    uint32_t d0 = *(const uint32_t*)(gFc + ((uint32_t)ma.x + ch4));
    uint32_t d1 = *(const uint32_t*)(gFc + ((uint32_t)ma.y + ch4));
    uint32_t d2 = *(const uint32_t*)(gFc + ((uint32_t)ma.z + ch4));
    uint32_t d3 = *(const uint32_t*)(gFc + ((uint32_t)ma.w + ch4));
    float4 wza = *(const float4*)&wz[mi];
    float4 wha = *(const float4*)&wh[mi];
    MACLO(az, wza.x, d0); MACHI(ah, wha.x, d0);
    MACLO(az, wza.y, d1); MACHI(ah, wha.y, d1);
    MACLO(az, wza.z, d2); MACHI(ah, wha.z, d2);
    MACLO(az, wza.w, d3); MACHI(ah, wha.w, d3);
  }
  az *= rsz;
  ah *= rsh;

  // ---- epilogue: ELU + bias + self -> fp16-packed pre-gate dword ----
  f16x2 sp = __builtin_bit_cast(f16x2, spd);
  float vz = az + bgz[ch]; vz = vz > 0.f ? vz : __expf(vz) - 1.f;
  float vh = ah + bgh[ch]; vh = vh > 0.f ? vh : __expf(vh) - 1.f;
  f16x2 pre = {(_Float16)(vz + (float)sp.x), (_Float16)(vh + (float)sp.y)};
  abuf[(size_t)(rb + nl) * 64 + ch] = __builtin_bit_cast(uint32_t, pre);
}

// ---------------------------------------------------------------------------
// GRU recurrence: one lane per (node, channel); 12-step serial chain on
// fp16-packed pre-gate values (25 MB coalesced read). BN fused at the end.
__global__ __launch_bounds__(256) void gru_k(
    const uint32_t* __restrict__ abuf,
    const float* __restrict__ gam, const float* __restrict__ bet,
    const float* __restrict__ mu, const float* __restrict__ var,
    float* __restrict__ out) {
  const int gtid = blockIdx.x * 256 + threadIdx.x;   // [0, NB*NN*64)
  const int node = gtid >> 6, ch = gtid & 63;
  const int b = node >> 11, nl = node & (NN - 1);
  float hc = 0.f;
#pragma unroll
  for (int t = 0; t < NT; t++) {
    f16x2 pre = __builtin_bit_cast(
        f16x2, abuf[(size_t)((b * NT + t) * NN + nl) * 64 + ch]);
    float zg = RCPF(1.f + __expf(-((float)pre.x + hc)));      // sigmoid
    float ta = (float)pre.y + hc;
    float tg = 1.f - 2.f * RCPF(__expf(2.f * ta) + 1.f);      // tanh
    hc = zg * hc + (1.f - zg) * tg;
  }
  out[gtid] = (hc - mu[ch]) * rsqrtf(var[ch] + 1e-3f) * gam[ch] + bet[ch];
}

// ---------------------------------------------------------------------------
extern "C" void kernel_launch(void* const* d_in, const int* in_sizes, int n_in,
                              void* d_out, int out_size, void* d_ws, size_t ws_size,
                              hipStream_t stream) {
  (void)in_sizes; (void)n_in; (void)out_size; (void)ws_size;
  const float* X   = (const float*)d_in[0];
  const float* bm  = (const float*)d_in[1];
  const float* Wz  = (const float*)d_in[2];
  const float* Zb  = (const float*)d_in[3];
  const float* Wh  = (const float*)d_in[4];
  const float* Hb  = (const float*)d_in[5];
  const float* Wgz = (const float*)d_in[6];
  const float* a1z = (const float*)d_in[7];
  const float* a2z = (const float*)d_in[8];
  const float* bgz = (const float*)d_in[9];
  const float* Wgh = (const float*)d_in[10];
  const float* a1h = (const float*)d_in[11];
  const float* a2h = (const float*)d_in[12];
  const float* bgh = (const float*)d_in[13];
  const float* gam = (const float*)d_in[14];
  const float* bet = (const float*)d_in[15];
  const float* mu  = (const float*)d_in[16];
  const float* var = (const float*)d_in[17];
  float* out = (float*)d_out;

  char* p = (char*)d_ws;
  uint32_t* gbufF = (uint32_t*)p; p += (size_t)NR * 64 * sizeof(uint32_t);  // 25 MB
  uint32_t* gbufS = (uint32_t*)p; p += (size_t)NR * 64 * sizeof(uint32_t);  // 25 MB
  float*    fbuf  = (float*)p;    p += (size_t)NR * 16 * sizeof(float);     // 6 MB
  uint32_t* abuf  = (uint32_t*)p; p += (size_t)NR * 64 * sizeof(uint32_t);  // 25 MB
  int*      adj   = (int*)p;      p += (size_t)NB * NN * MAXD * sizeof(int);// 2 MB
  int*      deg   = (int*)p;      p += (size_t)NB * NN * sizeof(int);       // 32 KB
  _Float16* W16   = (_Float16*)p; p += 272 * 64 * sizeof(_Float16);         // 34 KB
  float*    biasC = (float*)p;    p += 128 * sizeof(float);

  build_adj_k<<<dim3(NB * NN / 4 + 68), dim3(256), 0, stream>>>(
      bm, adj, deg, Wgz, Wgh, Wz, Wh, a1z, a2z, a1h, a2h, Zb, Hb, W16, biasC);
  mfma_gemm_k<<<dim3(NR / 64), dim3(256), 0, stream>>>(
      X, W16, biasC, gbufF, gbufS, fbuf);
  attn_k<<<dim3(NB * NN / 4, NT), dim3(256), 0, stream>>>(
      gbufF, gbufS, fbuf, adj, deg, bgz, bgh, abuf);
  gru_k<<<dim3(NB * NN * 64 / 256), dim3(256), 0, stream>>>(
      abuf, gam, bet, mu, var, out);
}